// Round 1
// baseline (597.788 us; speedup 1.0000x reference)
//
#include <hip/hip_runtime.h>
#include <math.h>

#define HID 128

// ---------------- utility kernels ----------------

__global__ void zero_int(int* p, int n) {
    int i = blockIdx.x * blockDim.x + threadIdx.x;
    if (i < n) p[i] = 0;
}

// in-degree histogram over dst
__global__ void hist_kernel(const int* __restrict__ dst, int* __restrict__ cnt, int E) {
    int e = blockIdx.x * blockDim.x + threadIdx.x;
    if (e < E) atomicAdd(&cnt[dst[e]], 1);
}

// 3-kernel exclusive scan (N <= 256*256)
__global__ void scan1(const int* __restrict__ cnt, int* __restrict__ excl,
                      int* __restrict__ bsum, int N) {
    __shared__ int sh[256];
    int tid = threadIdx.x;
    int gid = blockIdx.x * 256 + tid;
    int v = (gid < N) ? cnt[gid] : 0;
    sh[tid] = v;
    __syncthreads();
    for (int o = 1; o < 256; o <<= 1) {
        int t = (tid >= o) ? sh[tid - o] : 0;
        __syncthreads();
        sh[tid] += t;
        __syncthreads();
    }
    if (gid < N) excl[gid] = sh[tid] - v;   // exclusive within block
    if (tid == 255) bsum[blockIdx.x] = sh[255];
}

__global__ void scan2(int* __restrict__ bsum, int NB) {
    __shared__ int sh[256];
    int tid = threadIdx.x;
    int v = (tid < NB) ? bsum[tid] : 0;
    sh[tid] = v;
    __syncthreads();
    for (int o = 1; o < 256; o <<= 1) {
        int t = (tid >= o) ? sh[tid - o] : 0;
        __syncthreads();
        sh[tid] += t;
        __syncthreads();
    }
    if (tid < NB) bsum[tid] = sh[tid] - v;  // exclusive
}

__global__ void scan3(const int* __restrict__ cnt, int* __restrict__ rowptr,
                      const int* __restrict__ bsum, int* __restrict__ cursor,
                      float* __restrict__ dis, int N, int E) {
    int gid = blockIdx.x * blockDim.x + threadIdx.x;
    if (gid < N) {
        int r = rowptr[gid] + bsum[blockIdx.x];
        rowptr[gid] = r;
        cursor[gid] = r;
        // deg includes the self-loop -> always >= 1
        dis[gid] = rsqrtf((float)cnt[gid] + 1.0f);
    }
    if (gid == 0) rowptr[N] = E;
}

// bucket incoming edges: csr_src[pos] = src of each edge incoming to dst
__global__ void scatter_kernel(const int* __restrict__ src, const int* __restrict__ dst,
                               int* __restrict__ cursor, int* __restrict__ csr_src, int E) {
    int e = blockIdx.x * blockDim.x + threadIdx.x;
    if (e < E) {
        int pos = atomicAdd(&cursor[dst[e]], 1);
        csr_src[pos] = src[e];
    }
}

// xw = x @ W1   (x: [N,5], W1: [5,128])
__global__ void xw1_kernel(const float* __restrict__ x, const float* __restrict__ W1,
                           float* __restrict__ out, int N) {
    int idx = blockIdx.x * blockDim.x + threadIdx.x;  // n*128 + j
    if (idx < N * HID) {
        int n = idx >> 7, j = idx & 127;
        const float* xr = x + n * 5;
        float acc = xr[0] * W1[j];
        acc += xr[1] * W1[HID + j];
        acc += xr[2] * W1[2 * HID + j];
        acc += xr[3] * W1[3 * HID + j];
        acc += xr[4] * W1[4 * HID + j];
        out[idx] = acc;
    }
}

// GCN aggregation: out[n] = bias + dis[n]*( sum_{e in(n)} dis[s]*xw[s] + dis[n]*xw[n] )
// one wave (64 lanes) per node, float2 per lane
__global__ void aggregate_kernel(const float* __restrict__ xw, const int* __restrict__ csr_src,
                                 const int* __restrict__ rowptr, const float* __restrict__ dis,
                                 const float* __restrict__ bias, float* __restrict__ out,
                                 int N, int do_relu) {
    int wave = threadIdx.x >> 6;
    int lane = threadIdx.x & 63;
    int n = blockIdx.x * (blockDim.x >> 6) + wave;
    if (n >= N) return;
    int beg = rowptr[n], end = rowptr[n + 1];
    float dn = dis[n];
    int j = lane * 2;
    float ax = 0.f, ay = 0.f;
    for (int i = beg; i < end; ++i) {
        int s = csr_src[i];
        float w = dis[s];
        float2 v = *(const float2*)&xw[s * HID + j];
        ax += w * v.x;
        ay += w * v.y;
    }
    float2 sv = *(const float2*)&xw[n * HID + j];
    ax += dn * sv.x;
    ay += dn * sv.y;
    float r0 = bias[j] + dn * ax;
    float r1 = bias[j + 1] + dn * ay;
    if (do_relu) { r0 = fmaxf(r0, 0.f); r1 = fmaxf(r1, 0.f); }
    *(float2*)&out[n * HID + j] = make_float2(r0, r1);
}

// out[N,128] = in[N,128] @ W[128,128] (+ bias).  32 nodes per block, 256 threads.
// thread = (row_set rs in 0..7) x (col_group cg in 0..31); each thread: 4 nodes x 4 cols.
__launch_bounds__(256)
__global__ void gemm128_kernel(const float* __restrict__ in, const float* __restrict__ W,
                               const float* __restrict__ bias, float* __restrict__ out, int N) {
    __shared__ float sA[32][HID];   // 16 KB
    __shared__ float sW[64][HID];   // 32 KB (K staged in halves)
    int tid = threadIdx.x;
    int base = blockIdx.x * 32;

    // stage A tile: 32 nodes x 128, float4 coalesced
    for (int i = tid; i < 32 * HID / 4; i += 256) {
        int n = i >> 5;            // (i*4)/128
        int c = (i & 31) * 4;
        float4 v = make_float4(0.f, 0.f, 0.f, 0.f);
        if (base + n < N) v = *(const float4*)&in[(size_t)(base + n) * HID + c];
        *(float4*)&sA[n][c] = v;
    }

    int cg = tid & 31;
    int rs = tid >> 5;
    float4 acc[4];
    #pragma unroll
    for (int m = 0; m < 4; ++m) acc[m] = make_float4(0.f, 0.f, 0.f, 0.f);

    for (int kb = 0; kb < HID; kb += 64) {
        __syncthreads();
        for (int i = tid; i < 64 * HID / 4; i += 256) {
            int r = i >> 5;
            int c = (i & 31) * 4;
            *(float4*)&sW[r][c] = *(const float4*)&W[(size_t)(kb + r) * HID + c];
        }
        __syncthreads();
        #pragma unroll 8
        for (int k = 0; k < 64; ++k) {
            float4 w = *(float4*)&sW[k][cg * 4];
            #pragma unroll
            for (int m = 0; m < 4; ++m) {
                float a = sA[rs * 4 + m][kb + k];
                acc[m].x += a * w.x;
                acc[m].y += a * w.y;
                acc[m].z += a * w.z;
                acc[m].w += a * w.w;
            }
        }
    }

    float4 bv = make_float4(0.f, 0.f, 0.f, 0.f);
    if (bias) bv = *(const float4*)&bias[cg * 4];
    #pragma unroll
    for (int m = 0; m < 4; ++m) {
        int n = base + rs * 4 + m;
        if (n < N) {
            float4 r = make_float4(acc[m].x + bv.x, acc[m].y + bv.y,
                                   acc[m].z + bv.z, acc[m].w + bv.w);
            *(float4*)&out[(size_t)n * HID + cg * 4] = r;
        }
    }
}

// per-edge: out = sigmoid( dot(relu(Hs[src]+Hd[dst]+ea@Wb), Wm2) + bm2 )
// one wave per edge (grid-stride), float2 per lane, wave shuffle-reduce for the dot
__global__ void edge_mlp_kernel(const float* __restrict__ Hs, const float* __restrict__ Hd,
                                const float* __restrict__ ea, const int* __restrict__ src,
                                const int* __restrict__ dst, const float* __restrict__ Wb,
                                const float* __restrict__ Wm2, const float* __restrict__ bm2,
                                float* __restrict__ out, int E) {
    __shared__ float sWb[4 * HID];
    __shared__ float sW2[HID];
    int tid = threadIdx.x;
    for (int i = tid; i < 4 * HID; i += blockDim.x) sWb[i] = Wb[i];
    for (int i = tid; i < HID; i += blockDim.x) sW2[i] = Wm2[i];
    __syncthreads();
    float b2v = bm2[0];
    int lane = tid & 63;
    int gwave = (blockIdx.x * blockDim.x + tid) >> 6;
    int nwaves = (gridDim.x * blockDim.x) >> 6;
    int j = lane * 2;
    for (int e = gwave; e < E; e += nwaves) {
        int s = src[e];
        int d = dst[e];
        float4 eav = *(const float4*)&ea[(size_t)e * 4];
        float2 hs = *(const float2*)&Hs[(size_t)s * HID + j];
        float2 hd = *(const float2*)&Hd[(size_t)d * HID + j];
        float t0 = hs.x + hd.x + eav.x * sWb[j]     + eav.y * sWb[HID + j]
                               + eav.z * sWb[2*HID + j] + eav.w * sWb[3*HID + j];
        float t1 = hs.y + hd.y + eav.x * sWb[j+1]   + eav.y * sWb[HID + j+1]
                               + eav.z * sWb[2*HID + j+1] + eav.w * sWb[3*HID + j+1];
        t0 = fmaxf(t0, 0.f);
        t1 = fmaxf(t1, 0.f);
        float p = t0 * sW2[j] + t1 * sW2[j + 1];
        #pragma unroll
        for (int o = 32; o > 0; o >>= 1) p += __shfl_down(p, o, 64);
        if (lane == 0) out[e] = 1.f / (1.f + expf(-(p + b2v)));
    }
}

// ---------------- launch ----------------

extern "C" void kernel_launch(void* const* d_in, const int* in_sizes, int n_in,
                              void* d_out, int out_size, void* d_ws, size_t ws_size,
                              hipStream_t stream) {
    const float* x    = (const float*)d_in[0];
    const float* ea   = (const float*)d_in[1];
    const float* W1   = (const float*)d_in[2];
    const float* b1   = (const float*)d_in[3];
    const float* W2   = (const float*)d_in[4];
    const float* b2   = (const float*)d_in[5];
    const float* Wm1  = (const float*)d_in[6];
    const float* bm1  = (const float*)d_in[7];
    const float* Wm2  = (const float*)d_in[8];
    const float* bm2  = (const float*)d_in[9];
    const int*   ei   = (const int*)d_in[10];

    const int N = in_sizes[0] / 5;
    const int E = in_sizes[1] / 4;
    const int* src = ei;
    const int* dst = ei + E;
    float* out = (float*)d_out;

    // workspace bump allocator (256 B aligned)
    char* ws = (char*)d_ws;
    size_t off = 0;
    auto alloc = [&](size_t bytes) -> void* {
        void* p = ws + off;
        off = (off + bytes + 255) & ~(size_t)255;
        return p;
    };
    int*   cnt    = (int*)alloc((size_t)N * 4);
    int*   rowptr = (int*)alloc((size_t)(N + 1) * 4);
    int*   cursor = (int*)alloc((size_t)N * 4);
    int*   bsum   = (int*)alloc(256 * 4);
    float* dis    = (float*)alloc((size_t)N * 4);
    int*   csr    = (int*)alloc((size_t)E * 4);
    float* bufA   = (float*)alloc((size_t)N * HID * 4);   // xw1 -> xw2 -> Hs
    float* bufB   = (float*)alloc((size_t)N * HID * 4);   // h1 -> h
    float* Hd     = (float*)alloc((size_t)N * HID * 4);
    (void)ws_size; (void)n_in; (void)out_size;

    const int NB = (N + 255) / 256;       // 196 blocks, fits single-block scan2
    const int EB = (E + 255) / 256;

    // graph/CSR build
    zero_int<<<NB, 256, 0, stream>>>(cnt, N);
    hist_kernel<<<EB, 256, 0, stream>>>(dst, cnt, E);
    scan1<<<NB, 256, 0, stream>>>(cnt, rowptr, bsum, N);
    scan2<<<1, 256, 0, stream>>>(bsum, NB);
    scan3<<<NB, 256, 0, stream>>>(cnt, rowptr, bsum, cursor, dis, N, E);
    scatter_kernel<<<EB, 256, 0, stream>>>(src, dst, cursor, csr, E);

    // GCN layer 1
    xw1_kernel<<<(N * HID + 255) / 256, 256, 0, stream>>>(x, W1, bufA, N);
    aggregate_kernel<<<(N + 3) / 4, 256, 0, stream>>>(bufA, csr, rowptr, dis, b1, bufB, N, 1);

    // GCN layer 2
    gemm128_kernel<<<(N + 31) / 32, 256, 0, stream>>>(bufB, W2, nullptr, bufA, N);
    aggregate_kernel<<<(N + 3) / 4, 256, 0, stream>>>(bufA, csr, rowptr, dis, b2, bufB, N, 0);

    // edge MLP decomposition: Hs = h@Wm1[0:128] + bm1 ; Hd = h@Wm1[128:256]
    gemm128_kernel<<<(N + 31) / 32, 256, 0, stream>>>(bufB, Wm1, bm1, bufA, N);
    gemm128_kernel<<<(N + 31) / 32, 256, 0, stream>>>(bufB, Wm1 + 128 * HID, nullptr, Hd, N);

    // per-edge MLP + sigmoid
    edge_mlp_kernel<<<4096, 256, 0, stream>>>(bufA, Hd, ea, src, dst,
                                              Wm1 + 256 * HID, Wm2, bm2, out, E);
}

// Round 2
// 574.019 us; speedup vs baseline: 1.0414x; 1.0414x over previous
//
#include <hip/hip_runtime.h>
#include <math.h>

#define HID 128
typedef unsigned int uint;

// ---------------- bf16 pack/unpack (RNE) ----------------

__device__ __forceinline__ uint pack_bf2(float x, float y) {
    union { float f; uint u; } a, b;
    a.f = x; b.f = y;
    uint lo = (a.u + 0x7fffu + ((a.u >> 16) & 1u)) >> 16;
    uint hi = (b.u + 0x7fffu + ((b.u >> 16) & 1u)) & 0xffff0000u;
    return lo | hi;
}

__device__ __forceinline__ float2 unpack_bf2(uint v) {
    union { uint u; float f; } a, b;
    a.u = v << 16;
    b.u = v & 0xffff0000u;
    return make_float2(a.f, b.f);
}

// ---------------- CSR build ----------------

__global__ void zero_int(int* p, int n) {
    int i = blockIdx.x * blockDim.x + threadIdx.x;
    if (i < n) p[i] = 0;
}

__global__ void hist_kernel(const int* __restrict__ dst, int* __restrict__ cnt, int E) {
    int e = blockIdx.x * blockDim.x + threadIdx.x;
    if (e < E) atomicAdd(&cnt[dst[e]], 1);
}

__global__ void scan1(const int* __restrict__ cnt, int* __restrict__ excl,
                      int* __restrict__ bsum, int N) {
    __shared__ int sh[256];
    int tid = threadIdx.x;
    int gid = blockIdx.x * 256 + tid;
    int v = (gid < N) ? cnt[gid] : 0;
    sh[tid] = v;
    __syncthreads();
    for (int o = 1; o < 256; o <<= 1) {
        int t = (tid >= o) ? sh[tid - o] : 0;
        __syncthreads();
        sh[tid] += t;
        __syncthreads();
    }
    if (gid < N) excl[gid] = sh[tid] - v;
    if (tid == 255) bsum[blockIdx.x] = sh[255];
}

__global__ void scan2(int* __restrict__ bsum, int NB) {
    __shared__ int sh[256];
    int tid = threadIdx.x;
    int v = (tid < NB) ? bsum[tid] : 0;
    sh[tid] = v;
    __syncthreads();
    for (int o = 1; o < 256; o <<= 1) {
        int t = (tid >= o) ? sh[tid - o] : 0;
        __syncthreads();
        sh[tid] += t;
        __syncthreads();
    }
    if (tid < NB) bsum[tid] = sh[tid] - v;
}

__global__ void scan3(const int* __restrict__ cnt, int* __restrict__ rowptr,
                      const int* __restrict__ bsum, int* __restrict__ cursor,
                      float* __restrict__ dis, int N, int E) {
    int gid = blockIdx.x * blockDim.x + threadIdx.x;
    if (gid < N) {
        int r = rowptr[gid] + bsum[blockIdx.x];
        rowptr[gid] = r;
        cursor[gid] = r;
        dis[gid] = rsqrtf((float)cnt[gid] + 1.0f);   // deg incl. self-loop
    }
    if (gid == 0) rowptr[N] = E;
}

// csr[pos] = (src, edge_id) of each edge incoming to dst
__global__ void scatter_kernel(const int* __restrict__ src, const int* __restrict__ dst,
                               int* __restrict__ cursor, int2* __restrict__ csr, int E) {
    int e = blockIdx.x * blockDim.x + threadIdx.x;
    if (e < E) {
        int pos = atomicAdd(&cursor[dst[e]], 1);
        csr[pos] = make_int2(src[e], e);
    }
}

// ---------------- feature kernels ----------------

// xw1 = x @ W1, stored bf16-packed (uint = 2 cols)
__global__ void xw1_kernel(const float* __restrict__ x, const float* __restrict__ W1,
                           uint* __restrict__ out, int N) {
    int idx = blockIdx.x * blockDim.x + threadIdx.x;   // n*64 + pair
    if (idx < N * 64) {
        int n = idx >> 6, p = idx & 63;
        int j = p * 2;
        const float* xr = x + n * 5;
        float a0 = 0.f, a1 = 0.f;
        #pragma unroll
        for (int k = 0; k < 5; ++k) {
            a0 += xr[k] * W1[k * HID + j];
            a1 += xr[k] * W1[k * HID + j + 1];
        }
        out[idx] = pack_bf2(a0, a1);
    }
}

// GCN aggregation over bf16 rows: out[n] = bias + dis[n]*( sum dis[s]*xw[s] + dis[n]*xw[n] )
// one wave per node, 1 uint (2 bf16) per lane, fp32 accumulate, fp32 output
__global__ void aggregate_kernel(const uint* __restrict__ xw, const int2* __restrict__ csr,
                                 const int* __restrict__ rowptr, const float* __restrict__ dis,
                                 const float* __restrict__ bias, float* __restrict__ out,
                                 int N, int do_relu) {
    int wave = threadIdx.x >> 6;
    int lane = threadIdx.x & 63;
    int n = blockIdx.x * (blockDim.x >> 6) + wave;
    if (n >= N) return;
    int beg = rowptr[n], end = rowptr[n + 1];
    float dn = dis[n];
    float ax = 0.f, ay = 0.f;
    for (int i = beg; i < end; ++i) {
        int s = csr[i].x;
        float w = dis[s];
        float2 v = unpack_bf2(xw[(size_t)s * 64 + lane]);
        ax += w * v.x;
        ay += w * v.y;
    }
    float2 sv = unpack_bf2(xw[(size_t)n * 64 + lane]);
    ax += dn * sv.x;
    ay += dn * sv.y;
    int j = lane * 2;
    float r0 = bias[j] + dn * ax;
    float r1 = bias[j + 1] + dn * ay;
    if (do_relu) { r0 = fmaxf(r0, 0.f); r1 = fmaxf(r1, 0.f); }
    *(float2*)&out[(size_t)n * HID + j] = make_float2(r0, r1);
}

// out[N,128] = in[N,128] @ W[128,128] (+ bias), fp32 in, bf16-packed out.
__launch_bounds__(256)
__global__ void gemm128_kernel(const float* __restrict__ in, const float* __restrict__ W,
                               const float* __restrict__ bias, uint* __restrict__ out, int N) {
    __shared__ float sA[32][HID];
    __shared__ float sW[64][HID];
    int tid = threadIdx.x;
    int base = blockIdx.x * 32;

    for (int i = tid; i < 32 * HID / 4; i += 256) {
        int n = i >> 5;
        int c = (i & 31) * 4;
        float4 v = make_float4(0.f, 0.f, 0.f, 0.f);
        if (base + n < N) v = *(const float4*)&in[(size_t)(base + n) * HID + c];
        *(float4*)&sA[n][c] = v;
    }

    int cg = tid & 31;
    int rs = tid >> 5;
    float4 acc[4];
    #pragma unroll
    for (int m = 0; m < 4; ++m) acc[m] = make_float4(0.f, 0.f, 0.f, 0.f);

    for (int kb = 0; kb < HID; kb += 64) {
        __syncthreads();
        for (int i = tid; i < 64 * HID / 4; i += 256) {
            int r = i >> 5;
            int c = (i & 31) * 4;
            *(float4*)&sW[r][c] = *(const float4*)&W[(size_t)(kb + r) * HID + c];
        }
        __syncthreads();
        #pragma unroll 8
        for (int k = 0; k < 64; ++k) {
            float4 w = *(float4*)&sW[k][cg * 4];
            #pragma unroll
            for (int m = 0; m < 4; ++m) {
                float a = sA[rs * 4 + m][kb + k];
                acc[m].x += a * w.x;
                acc[m].y += a * w.y;
                acc[m].z += a * w.z;
                acc[m].w += a * w.w;
            }
        }
    }

    float4 bv = make_float4(0.f, 0.f, 0.f, 0.f);
    if (bias) bv = *(const float4*)&bias[cg * 4];
    #pragma unroll
    for (int m = 0; m < 4; ++m) {
        int n = base + rs * 4 + m;
        if (n < N) {
            uint2 pk;
            pk.x = pack_bf2(acc[m].x + bv.x, acc[m].y + bv.y);
            pk.y = pack_bf2(acc[m].z + bv.z, acc[m].w + bv.w);
            *(uint2*)&out[(size_t)n * 64 + cg * 2] = pk;
        }
    }
}

// per-dst-node edge MLP: wave per node, Hd row held in registers, loop incoming edges.
// out[eid] = sigmoid( dot(relu(Hs[src]+Hd[n]+ea[eid]@Wb), Wm2) + bm2 )
__global__ void edge_mlp_kernel(const uint* __restrict__ Hs, const uint* __restrict__ Hd,
                                const float* __restrict__ ea, const int2* __restrict__ csr,
                                const int* __restrict__ rowptr,
                                const float* __restrict__ Wb, const float* __restrict__ Wm2,
                                const float* __restrict__ bm2,
                                float* __restrict__ out, int N) {
    __shared__ float sWb[4 * HID];
    __shared__ float sW2[HID];
    int tid = threadIdx.x;
    for (int i = tid; i < 4 * HID; i += blockDim.x) sWb[i] = Wb[i];
    for (int i = tid; i < HID; i += blockDim.x) sW2[i] = Wm2[i];
    __syncthreads();

    int wave = tid >> 6;
    int lane = tid & 63;
    int n = blockIdx.x * (blockDim.x >> 6) + wave;
    if (n >= N) return;
    int beg = rowptr[n], end = rowptr[n + 1];
    if (beg == end) return;

    float b2v = bm2[0];
    int j = lane * 2;
    float2 hd = unpack_bf2(Hd[(size_t)n * 64 + lane]);
    float w20 = sW2[j], w21 = sW2[j + 1];
    float wb00 = sWb[j],           wb01 = sWb[j + 1];
    float wb10 = sWb[HID + j],     wb11 = sWb[HID + j + 1];
    float wb20 = sWb[2 * HID + j], wb21 = sWb[2 * HID + j + 1];
    float wb30 = sWb[3 * HID + j], wb31 = sWb[3 * HID + j + 1];

    for (int i = beg; i < end; ++i) {
        int2 ce = csr[i];                                    // broadcast 8B
        float2 hs = unpack_bf2(Hs[(size_t)ce.x * 64 + lane]);
        float4 eav = *(const float4*)&ea[(size_t)ce.y * 4];  // broadcast 16B
        float t0 = hs.x + hd.x + eav.x * wb00 + eav.y * wb10 + eav.z * wb20 + eav.w * wb30;
        float t1 = hs.y + hd.y + eav.x * wb01 + eav.y * wb11 + eav.z * wb21 + eav.w * wb31;
        t0 = fmaxf(t0, 0.f);
        t1 = fmaxf(t1, 0.f);
        float p = t0 * w20 + t1 * w21;
        #pragma unroll
        for (int o = 32; o > 0; o >>= 1) p += __shfl_down(p, o, 64);
        if (lane == 0) out[ce.y] = 1.f / (1.f + expf(-(p + b2v)));
    }
}

// ---------------- launch ----------------

extern "C" void kernel_launch(void* const* d_in, const int* in_sizes, int n_in,
                              void* d_out, int out_size, void* d_ws, size_t ws_size,
                              hipStream_t stream) {
    const float* x    = (const float*)d_in[0];
    const float* ea   = (const float*)d_in[1];
    const float* W1   = (const float*)d_in[2];
    const float* b1   = (const float*)d_in[3];
    const float* W2   = (const float*)d_in[4];
    const float* b2   = (const float*)d_in[5];
    const float* Wm1  = (const float*)d_in[6];
    const float* bm1  = (const float*)d_in[7];
    const float* Wm2  = (const float*)d_in[8];
    const float* bm2  = (const float*)d_in[9];
    const int*   ei   = (const int*)d_in[10];

    const int N = in_sizes[0] / 5;
    const int E = in_sizes[1] / 4;
    const int* src = ei;
    const int* dst = ei + E;
    float* out = (float*)d_out;

    char* ws = (char*)d_ws;
    size_t off = 0;
    auto alloc = [&](size_t bytes) -> void* {
        void* p = ws + off;
        off = (off + bytes + 255) & ~(size_t)255;
        return p;
    };
    int*   cnt    = (int*)alloc((size_t)N * 4);
    int*   rowptr = (int*)alloc((size_t)(N + 1) * 4);
    int*   cursor = (int*)alloc((size_t)N * 4);
    int*   bsum   = (int*)alloc(256 * 4);
    float* dis    = (float*)alloc((size_t)N * 4);
    int2*  csr    = (int2*)alloc((size_t)E * 8);
    uint*  bufA   = (uint*)alloc((size_t)N * 64 * 4);     // bf16 xw1 -> xw2 -> Hs
    float* bufB   = (float*)alloc((size_t)N * HID * 4);   // fp32 h1 -> h
    uint*  Hd     = (uint*)alloc((size_t)N * 64 * 4);     // bf16
    (void)ws_size; (void)n_in; (void)out_size;

    const int NB = (N + 255) / 256;
    const int EB = (E + 255) / 256;

    // CSR build
    zero_int<<<NB, 256, 0, stream>>>(cnt, N);
    hist_kernel<<<EB, 256, 0, stream>>>(dst, cnt, E);
    scan1<<<NB, 256, 0, stream>>>(cnt, rowptr, bsum, N);
    scan2<<<1, 256, 0, stream>>>(bsum, NB);
    scan3<<<NB, 256, 0, stream>>>(cnt, rowptr, bsum, cursor, dis, N, E);
    scatter_kernel<<<EB, 256, 0, stream>>>(src, dst, cursor, csr, E);

    // GCN layer 1
    xw1_kernel<<<(N * 64 + 255) / 256, 256, 0, stream>>>(x, W1, bufA, N);
    aggregate_kernel<<<(N + 3) / 4, 256, 0, stream>>>(bufA, csr, rowptr, dis, b1, bufB, N, 1);

    // GCN layer 2
    gemm128_kernel<<<(N + 31) / 32, 256, 0, stream>>>(bufB, W2, nullptr, bufA, N);
    aggregate_kernel<<<(N + 3) / 4, 256, 0, stream>>>(bufA, csr, rowptr, dis, b2, bufB, N, 0);

    // edge MLP decomposition: Hs = h@Wm1[0:128] + bm1 ; Hd = h@Wm1[128:256]
    gemm128_kernel<<<(N + 31) / 32, 256, 0, stream>>>(bufB, Wm1, bm1, bufA, N);
    gemm128_kernel<<<(N + 31) / 32, 256, 0, stream>>>(bufB, Wm1 + 128 * HID, nullptr, Hd, N);

    // per-edge MLP + sigmoid, dst-grouped via CSR
    edge_mlp_kernel<<<(N + 3) / 4, 256, 0, stream>>>(bufA, Hd, ea, csr, rowptr,
                                                     Wm1 + 256 * HID, Wm2, bm2, out, N);
}

// Round 3
// 427.715 us; speedup vs baseline: 1.3976x; 1.3421x over previous
//
#include <hip/hip_runtime.h>
#include <math.h>

#define HID 128
typedef unsigned int uint;

// ---------------- bf16 pack/unpack (RNE) ----------------

__device__ __forceinline__ uint pack_bf2(float x, float y) {
    union { float f; uint u; } a, b;
    a.f = x; b.f = y;
    uint lo = (a.u + 0x7fffu + ((a.u >> 16) & 1u)) >> 16;
    uint hi = (b.u + 0x7fffu + ((b.u >> 16) & 1u)) & 0xffff0000u;
    return lo | hi;
}

__device__ __forceinline__ float2 unpack_bf2(uint v) {
    union { uint u; float f; } a, b;
    a.u = v << 16;
    b.u = v & 0xffff0000u;
    return make_float2(a.f, b.f);
}

__device__ __forceinline__ void unpack_bf8(uint4 v, float* f) {
    float2 a = unpack_bf2(v.x); f[0] = a.x; f[1] = a.y;
    float2 b = unpack_bf2(v.y); f[2] = b.x; f[3] = b.y;
    float2 c = unpack_bf2(v.z); f[4] = c.x; f[5] = c.y;
    float2 d = unpack_bf2(v.w); f[6] = d.x; f[7] = d.y;
}

// ---------------- CSR build ----------------

__global__ void zero_int(int* p, int n) {
    int i = blockIdx.x * blockDim.x + threadIdx.x;
    if (i < n) p[i] = 0;
}

__global__ void hist_kernel(const int* __restrict__ dst, int* __restrict__ cnt, int E) {
    int e = blockIdx.x * blockDim.x + threadIdx.x;
    if (e < E) atomicAdd(&cnt[dst[e]], 1);
}

__global__ void scan1(const int* __restrict__ cnt, int* __restrict__ excl,
                      int* __restrict__ bsum, int N) {
    __shared__ int sh[256];
    int tid = threadIdx.x;
    int gid = blockIdx.x * 256 + tid;
    int v = (gid < N) ? cnt[gid] : 0;
    sh[tid] = v;
    __syncthreads();
    for (int o = 1; o < 256; o <<= 1) {
        int t = (tid >= o) ? sh[tid - o] : 0;
        __syncthreads();
        sh[tid] += t;
        __syncthreads();
    }
    if (gid < N) excl[gid] = sh[tid] - v;
    if (tid == 255) bsum[blockIdx.x] = sh[255];
}

__global__ void scan2(int* __restrict__ bsum, int NB) {
    __shared__ int sh[256];
    int tid = threadIdx.x;
    int v = (tid < NB) ? bsum[tid] : 0;
    sh[tid] = v;
    __syncthreads();
    for (int o = 1; o < 256; o <<= 1) {
        int t = (tid >= o) ? sh[tid - o] : 0;
        __syncthreads();
        sh[tid] += t;
        __syncthreads();
    }
    if (tid < NB) bsum[tid] = sh[tid] - v;
}

__global__ void scan3(const int* __restrict__ cnt, int* __restrict__ rowptr,
                      const int* __restrict__ bsum, int* __restrict__ cursor,
                      float* __restrict__ dis, int N, int E) {
    int gid = blockIdx.x * blockDim.x + threadIdx.x;
    if (gid < N) {
        int r = rowptr[gid] + bsum[blockIdx.x];
        rowptr[gid] = r;
        cursor[gid] = r;
        dis[gid] = rsqrtf((float)cnt[gid] + 1.0f);   // deg incl. self-loop
    }
    if (gid == 0) rowptr[N] = E;
}

// csr[pos] = (src, edge_id) of each edge incoming to dst
__global__ void scatter_kernel(const int* __restrict__ src, const int* __restrict__ dst,
                               int* __restrict__ cursor, int2* __restrict__ csr, int E) {
    int e = blockIdx.x * blockDim.x + threadIdx.x;
    if (e < E) {
        int pos = atomicAdd(&cursor[dst[e]], 1);
        csr[pos] = make_int2(src[e], e);
    }
}

// ---------------- feature kernels ----------------

// xws1 = dis[n] * (x @ W1), stored bf16-packed
__global__ void xw1_kernel(const float* __restrict__ x, const float* __restrict__ W1,
                           const float* __restrict__ dis, uint* __restrict__ out, int N) {
    int idx = blockIdx.x * blockDim.x + threadIdx.x;   // n*64 + pair
    if (idx < N * 64) {
        int n = idx >> 6, p = idx & 63;
        int j = p * 2;
        const float* xr = x + n * 5;
        float a0 = 0.f, a1 = 0.f;
        #pragma unroll
        for (int k = 0; k < 5; ++k) {
            a0 += xr[k] * W1[k * HID + j];
            a1 += xr[k] * W1[k * HID + j + 1];
        }
        float dn = dis[n];
        out[idx] = pack_bf2(a0 * dn, a1 * dn);
    }
}

// GCN aggregation: out[n] = bias + dis[n]*( sum_{in(n)} xws[s] + xws[n] )
// wave per node; 16-lane group per edge, 4 edges in flight; 8 dims (uint4) per lane.
__global__ void aggregate_kernel(const uint4* __restrict__ xws, const int2* __restrict__ csr,
                                 const int* __restrict__ rowptr, const float* __restrict__ dis,
                                 const float* __restrict__ bias, float* __restrict__ out,
                                 int N, int do_relu) {
    int wave = threadIdx.x >> 6;
    int lane = threadIdx.x & 63;
    int n = blockIdx.x * (blockDim.x >> 6) + wave;
    if (n >= N) return;
    int gl = lane & 15, grp = lane >> 4;
    int beg = rowptr[n], end = rowptr[n + 1];

    float acc[8];
    #pragma unroll
    for (int j = 0; j < 8; ++j) acc[j] = 0.f;

    int itn = (end - beg + 3) >> 2;
    for (int it = 0; it < itn; ++it) {
        int idx = beg + it * 4 + grp;
        bool valid = idx < end;
        int s = csr[valid ? idx : beg].x;
        uint4 v = xws[(size_t)s * 16 + gl];
        float f[8];
        unpack_bf8(v, f);
        if (valid) {
            #pragma unroll
            for (int j = 0; j < 8; ++j) acc[j] += f[j];
        }
    }
    // combine the 4 groups (all hold the same 8 dims)
    #pragma unroll
    for (int j = 0; j < 8; ++j) {
        acc[j] += __shfl_xor(acc[j], 16, 64);
        acc[j] += __shfl_xor(acc[j], 32, 64);
    }

    if (grp == 0) {
        float f[8];
        unpack_bf8(xws[(size_t)n * 16 + gl], f);
        float dn = dis[n];
        const float4* b4 = (const float4*)(bias + gl * 8);
        float4 b0 = b4[0], b1 = b4[1];
        float o[8];
        o[0] = b0.x + dn * (acc[0] + f[0]);
        o[1] = b0.y + dn * (acc[1] + f[1]);
        o[2] = b0.z + dn * (acc[2] + f[2]);
        o[3] = b0.w + dn * (acc[3] + f[3]);
        o[4] = b1.x + dn * (acc[4] + f[4]);
        o[5] = b1.y + dn * (acc[5] + f[5]);
        o[6] = b1.z + dn * (acc[6] + f[6]);
        o[7] = b1.w + dn * (acc[7] + f[7]);
        if (do_relu) {
            #pragma unroll
            for (int j = 0; j < 8; ++j) o[j] = fmaxf(o[j], 0.f);
        }
        float* op = out + (size_t)n * HID + gl * 8;
        *(float4*)op       = make_float4(o[0], o[1], o[2], o[3]);
        *(float4*)(op + 4) = make_float4(o[4], o[5], o[6], o[7]);
    }
}

// out[N,128] = (in[N,128] @ W[128,128] + bias) * rowscale, bf16-packed out.
__launch_bounds__(256)
__global__ void gemm128_kernel(const float* __restrict__ in, const float* __restrict__ W,
                               const float* __restrict__ bias, const float* __restrict__ rowscale,
                               uint* __restrict__ out, int N) {
    __shared__ float sA[32][HID];
    __shared__ float sW[64][HID];
    int tid = threadIdx.x;
    int base = blockIdx.x * 32;

    for (int i = tid; i < 32 * HID / 4; i += 256) {
        int n = i >> 5;
        int c = (i & 31) * 4;
        float4 v = make_float4(0.f, 0.f, 0.f, 0.f);
        if (base + n < N) v = *(const float4*)&in[(size_t)(base + n) * HID + c];
        *(float4*)&sA[n][c] = v;
    }

    int cg = tid & 31;
    int rs = tid >> 5;
    float4 acc[4];
    #pragma unroll
    for (int m = 0; m < 4; ++m) acc[m] = make_float4(0.f, 0.f, 0.f, 0.f);

    for (int kb = 0; kb < HID; kb += 64) {
        __syncthreads();
        for (int i = tid; i < 64 * HID / 4; i += 256) {
            int r = i >> 5;
            int c = (i & 31) * 4;
            *(float4*)&sW[r][c] = *(const float4*)&W[(size_t)(kb + r) * HID + c];
        }
        __syncthreads();
        #pragma unroll 8
        for (int k = 0; k < 64; ++k) {
            float4 w = *(float4*)&sW[k][cg * 4];
            #pragma unroll
            for (int m = 0; m < 4; ++m) {
                float a = sA[rs * 4 + m][kb + k];
                acc[m].x += a * w.x;
                acc[m].y += a * w.y;
                acc[m].z += a * w.z;
                acc[m].w += a * w.w;
            }
        }
    }

    float4 bv = make_float4(0.f, 0.f, 0.f, 0.f);
    if (bias) bv = *(const float4*)&bias[cg * 4];
    #pragma unroll
    for (int m = 0; m < 4; ++m) {
        int n = base + rs * 4 + m;
        if (n < N) {
            float sc = rowscale ? rowscale[n] : 1.f;
            uint2 pk;
            pk.x = pack_bf2((acc[m].x + bv.x) * sc, (acc[m].y + bv.y) * sc);
            pk.y = pack_bf2((acc[m].z + bv.z) * sc, (acc[m].w + bv.w) * sc);
            *(uint2*)&out[(size_t)n * 64 + cg * 2] = pk;
        }
    }
}

// dst-grouped edge MLP: wave per node, 16-lane group per edge (4 edges in flight),
// 8 dims per lane; Hd row + weights held in registers across the edge loop.
__global__ void edge_mlp_kernel(const uint4* __restrict__ Hs, const uint4* __restrict__ Hd,
                                const float4* __restrict__ ea, const int2* __restrict__ csr,
                                const int* __restrict__ rowptr,
                                const float* __restrict__ Wb, const float* __restrict__ Wm2,
                                const float* __restrict__ bm2,
                                float* __restrict__ out, int N) {
    int wave = threadIdx.x >> 6;
    int lane = threadIdx.x & 63;
    int n = blockIdx.x * (blockDim.x >> 6) + wave;
    if (n >= N) return;
    int beg = rowptr[n], end = rowptr[n + 1];
    if (beg == end) return;
    int gl = lane & 15, grp = lane >> 4;

    float hd[8];
    unpack_bf8(Hd[(size_t)n * 16 + gl], hd);

    float wb[4][8];
    #pragma unroll
    for (int k = 0; k < 4; ++k) {
        const float4* w4 = (const float4*)(Wb + k * HID + gl * 8);
        float4 a = w4[0], b = w4[1];
        wb[k][0] = a.x; wb[k][1] = a.y; wb[k][2] = a.z; wb[k][3] = a.w;
        wb[k][4] = b.x; wb[k][5] = b.y; wb[k][6] = b.z; wb[k][7] = b.w;
    }
    float w2[8];
    {
        const float4* w4 = (const float4*)(Wm2 + gl * 8);
        float4 a = w4[0], b = w4[1];
        w2[0] = a.x; w2[1] = a.y; w2[2] = a.z; w2[3] = a.w;
        w2[4] = b.x; w2[5] = b.y; w2[6] = b.z; w2[7] = b.w;
    }
    float b2v = bm2[0];

    int itn = (end - beg + 3) >> 2;
    for (int it = 0; it < itn; ++it) {
        int idx = beg + it * 4 + grp;
        bool valid = idx < end;
        int2 ce = csr[valid ? idx : beg];
        uint4 hv = Hs[(size_t)ce.x * 16 + gl];
        float4 eav = ea[ce.y];
        float hs[8];
        unpack_bf8(hv, hs);
        float p = 0.f;
        #pragma unroll
        for (int j = 0; j < 8; ++j) {
            float t = hs[j] + hd[j] + eav.x * wb[0][j] + eav.y * wb[1][j]
                                    + eav.z * wb[2][j] + eav.w * wb[3][j];
            t = fmaxf(t, 0.f);
            p += t * w2[j];
        }
        // reduce within each 16-lane group (4 edges reduced simultaneously)
        p += __shfl_xor(p, 1, 64);
        p += __shfl_xor(p, 2, 64);
        p += __shfl_xor(p, 4, 64);
        p += __shfl_xor(p, 8, 64);
        if (valid && gl == 0) out[ce.y] = 1.f / (1.f + expf(-(p + b2v)));
    }
}

// ---------------- launch ----------------

extern "C" void kernel_launch(void* const* d_in, const int* in_sizes, int n_in,
                              void* d_out, int out_size, void* d_ws, size_t ws_size,
                              hipStream_t stream) {
    const float* x    = (const float*)d_in[0];
    const float* ea   = (const float*)d_in[1];
    const float* W1   = (const float*)d_in[2];
    const float* b1   = (const float*)d_in[3];
    const float* W2   = (const float*)d_in[4];
    const float* b2   = (const float*)d_in[5];
    const float* Wm1  = (const float*)d_in[6];
    const float* bm1  = (const float*)d_in[7];
    const float* Wm2  = (const float*)d_in[8];
    const float* bm2  = (const float*)d_in[9];
    const int*   ei   = (const int*)d_in[10];

    const int N = in_sizes[0] / 5;
    const int E = in_sizes[1] / 4;
    const int* src = ei;
    const int* dst = ei + E;
    float* out = (float*)d_out;

    char* ws = (char*)d_ws;
    size_t off = 0;
    auto alloc = [&](size_t bytes) -> void* {
        void* p = ws + off;
        off = (off + bytes + 255) & ~(size_t)255;
        return p;
    };
    int*   cnt    = (int*)alloc((size_t)N * 4);
    int*   rowptr = (int*)alloc((size_t)(N + 1) * 4);
    int*   cursor = (int*)alloc((size_t)N * 4);
    int*   bsum   = (int*)alloc(256 * 4);
    float* dis    = (float*)alloc((size_t)N * 4);
    int2*  csr    = (int2*)alloc((size_t)E * 8);
    uint*  bufA   = (uint*)alloc((size_t)N * 64 * 4);     // bf16: xws1 -> xws2 -> Hs
    float* bufB   = (float*)alloc((size_t)N * HID * 4);   // fp32: h1 -> h
    uint*  Hd     = (uint*)alloc((size_t)N * 64 * 4);     // bf16
    (void)ws_size; (void)n_in; (void)out_size;

    const int NB = (N + 255) / 256;
    const int EB = (E + 255) / 256;

    // CSR build
    zero_int<<<NB, 256, 0, stream>>>(cnt, N);
    hist_kernel<<<EB, 256, 0, stream>>>(dst, cnt, E);
    scan1<<<NB, 256, 0, stream>>>(cnt, rowptr, bsum, N);
    scan2<<<1, 256, 0, stream>>>(bsum, NB);
    scan3<<<NB, 256, 0, stream>>>(cnt, rowptr, bsum, cursor, dis, N, E);
    scatter_kernel<<<EB, 256, 0, stream>>>(src, dst, cursor, csr, E);

    // GCN layer 1 (dis pre-folded into features)
    xw1_kernel<<<(N * 64 + 255) / 256, 256, 0, stream>>>(x, W1, dis, bufA, N);
    aggregate_kernel<<<(N + 3) / 4, 256, 0, stream>>>((const uint4*)bufA, csr, rowptr, dis,
                                                      b1, bufB, N, 1);

    // GCN layer 2 (rowscale folds dis into xws2 at pack time)
    gemm128_kernel<<<(N + 31) / 32, 256, 0, stream>>>(bufB, W2, nullptr, dis, bufA, N);
    aggregate_kernel<<<(N + 3) / 4, 256, 0, stream>>>((const uint4*)bufA, csr, rowptr, dis,
                                                      b2, bufB, N, 0);

    // edge MLP decomposition: Hs = h@Wm1[0:128] + bm1 ; Hd = h@Wm1[128:256]
    gemm128_kernel<<<(N + 31) / 32, 256, 0, stream>>>(bufB, Wm1, bm1, nullptr, bufA, N);
    gemm128_kernel<<<(N + 31) / 32, 256, 0, stream>>>(bufB, Wm1 + 128 * HID, nullptr, nullptr, Hd, N);

    // per-edge MLP + sigmoid, dst-grouped via CSR
    edge_mlp_kernel<<<(N + 3) / 4, 256, 0, stream>>>((const uint4*)bufA, (const uint4*)Hd,
                                                     (const float4*)ea, csr, rowptr,
                                                     Wm1 + 256 * HID, Wm2, bm2, out, N);
}

// Round 4
// 377.456 us; speedup vs baseline: 1.5837x; 1.1332x over previous
//
#include <hip/hip_runtime.h>
#include <math.h>

#define HID 128
typedef unsigned int uint;
typedef __attribute__((ext_vector_type(8))) __bf16 bf16x8;
typedef __attribute__((ext_vector_type(4))) float f32x4;

// ---------------- bf16 pack/unpack (RNE) ----------------

__device__ __forceinline__ uint pack_bf2(float x, float y) {
    union { float f; uint u; } a, b;
    a.f = x; b.f = y;
    uint lo = (a.u + 0x7fffu + ((a.u >> 16) & 1u)) >> 16;
    uint hi = (b.u + 0x7fffu + ((b.u >> 16) & 1u)) & 0xffff0000u;
    return lo | hi;
}

__device__ __forceinline__ unsigned short bf16r(float x) {
    union { float f; uint u; } a; a.f = x;
    return (unsigned short)((a.u + 0x7fffu + ((a.u >> 16) & 1u)) >> 16);
}

__device__ __forceinline__ float2 unpack_bf2(uint v) {
    union { uint u; float f; } a, b;
    a.u = v << 16;
    b.u = v & 0xffff0000u;
    return make_float2(a.f, b.f);
}

__device__ __forceinline__ void unpack_bf8(uint4 v, float* f) {
    float2 a = unpack_bf2(v.x); f[0] = a.x; f[1] = a.y;
    float2 b = unpack_bf2(v.y); f[2] = b.x; f[3] = b.y;
    float2 c = unpack_bf2(v.z); f[4] = c.x; f[5] = c.y;
    float2 d = unpack_bf2(v.w); f[6] = d.x; f[7] = d.y;
}

// ---------------- CSR build ----------------

__global__ void zero_int(int* p, int n) {
    int i = blockIdx.x * blockDim.x + threadIdx.x;
    if (i < n) p[i] = 0;
}

__global__ void hist_kernel(const int* __restrict__ dst, int* __restrict__ cnt, int E) {
    int e = blockIdx.x * blockDim.x + threadIdx.x;
    if (e < E) atomicAdd(&cnt[dst[e]], 1);
}

__global__ void scan1(const int* __restrict__ cnt, int* __restrict__ excl,
                      int* __restrict__ bsum, int N) {
    __shared__ int sh[256];
    int tid = threadIdx.x;
    int gid = blockIdx.x * 256 + tid;
    int v = (gid < N) ? cnt[gid] : 0;
    sh[tid] = v;
    __syncthreads();
    for (int o = 1; o < 256; o <<= 1) {
        int t = (tid >= o) ? sh[tid - o] : 0;
        __syncthreads();
        sh[tid] += t;
        __syncthreads();
    }
    if (gid < N) excl[gid] = sh[tid] - v;
    if (tid == 255) bsum[blockIdx.x] = sh[255];
}

__global__ void scan2(int* __restrict__ bsum, int NB) {
    __shared__ int sh[256];
    int tid = threadIdx.x;
    int v = (tid < NB) ? bsum[tid] : 0;
    sh[tid] = v;
    __syncthreads();
    for (int o = 1; o < 256; o <<= 1) {
        int t = (tid >= o) ? sh[tid - o] : 0;
        __syncthreads();
        sh[tid] += t;
        __syncthreads();
    }
    if (tid < NB) bsum[tid] = sh[tid] - v;
}

__global__ void scan3(const int* __restrict__ cnt, int* __restrict__ rowptr,
                      const int* __restrict__ bsum, int* __restrict__ cursor,
                      float* __restrict__ dis, int N, int E) {
    int gid = blockIdx.x * blockDim.x + threadIdx.x;
    if (gid < N) {
        int r = rowptr[gid] + bsum[blockIdx.x];
        rowptr[gid] = r;
        cursor[gid] = r;
        dis[gid] = rsqrtf((float)cnt[gid] + 1.0f);   // deg incl. self-loop
    }
    if (gid == 0) rowptr[N] = E;
}

__global__ void scatter_kernel(const int* __restrict__ src, const int* __restrict__ dst,
                               int* __restrict__ cursor, int2* __restrict__ csr, int E) {
    int e = blockIdx.x * blockDim.x + threadIdx.x;
    if (e < E) {
        int pos = atomicAdd(&cursor[dst[e]], 1);
        csr[pos] = make_int2(src[e], e);
    }
}

// ---------------- weight prep: fp32 -> bf16 MFMA fragment order ----------------
// frag element for (ct, kk, lane, j):  B[k = kk*32 + (lane>>4)*8 + j][n = ct*16 + (lane&15)]
// stored as uint pairs (j = 2p, 2p+1). fW2: 8 ct (W2 128x128). fWm1: 16 ct (fused 128x256:
// cols 0..127 = Wm1 rows 0..127 (Hs), cols 128..255 = Wm1 rows 128..255 (Hd)).
__global__ void prep_frags(const float* __restrict__ W2, const float* __restrict__ Wm1,
                           uint* __restrict__ fW2, uint* __restrict__ fWm1) {
    int idx = blockIdx.x * blockDim.x + threadIdx.x;   // pair index
    if (idx < 8192) {          // 8 ct * 4 kk * 64 lanes * 4 pairs
        int p = idx & 3;
        int lane = (idx >> 2) & 63;
        int kk = (idx >> 8) & 3;
        int ct = idx >> 10;
        int k = kk * 32 + (lane >> 4) * 8 + p * 2;
        int n = ct * 16 + (lane & 15);
        fW2[idx] = pack_bf2(W2[k * HID + n], W2[(k + 1) * HID + n]);
    } else if (idx < 8192 + 16384) {
        int i = idx - 8192;
        int p = i & 3;
        int lane = (i >> 2) & 63;
        int kk = (i >> 8) & 3;
        int ct = i >> 10;
        int k = kk * 32 + (lane >> 4) * 8 + p * 2;
        int n = ct * 16 + (lane & 15);
        float v0, v1;
        if (n < 128) { v0 = Wm1[k * HID + n];         v1 = Wm1[(k + 1) * HID + n]; }
        else         { v0 = Wm1[(128 + k) * HID + n - 128]; v1 = Wm1[(129 + k) * HID + n - 128]; }
        fWm1[i] = pack_bf2(v0, v1);
    }
}

// ---------------- feature kernels ----------------

// xws1 = dis[n] * (x @ W1), bf16-packed
__global__ void xw1_kernel(const float* __restrict__ x, const float* __restrict__ W1,
                           const float* __restrict__ dis, uint* __restrict__ out, int N) {
    int idx = blockIdx.x * blockDim.x + threadIdx.x;
    if (idx < N * 64) {
        int n = idx >> 6, p = idx & 63;
        int j = p * 2;
        const float* xr = x + n * 5;
        float a0 = 0.f, a1 = 0.f;
        #pragma unroll
        for (int k = 0; k < 5; ++k) {
            a0 += xr[k] * W1[k * HID + j];
            a1 += xr[k] * W1[k * HID + j + 1];
        }
        float dn = dis[n];
        out[idx] = pack_bf2(a0 * dn, a1 * dn);
    }
}

// GCN aggregation: out[n] = bias + dis[n]*( sum_{in(n)} xws[s] + xws[n] ), bf16 out.
// wave per node; 16-lane group per edge, 4 edges in flight; 8 dims (uint4) per lane.
__global__ void aggregate_kernel(const uint4* __restrict__ xws, const int2* __restrict__ csr,
                                 const int* __restrict__ rowptr, const float* __restrict__ dis,
                                 const float* __restrict__ bias, uint4* __restrict__ out,
                                 int N, int do_relu) {
    int wave = threadIdx.x >> 6;
    int lane = threadIdx.x & 63;
    int n = blockIdx.x * (blockDim.x >> 6) + wave;
    if (n >= N) return;
    int gl = lane & 15, grp = lane >> 4;
    int beg = rowptr[n], end = rowptr[n + 1];

    float acc[8];
    #pragma unroll
    for (int j = 0; j < 8; ++j) acc[j] = 0.f;

    int itn = (end - beg + 3) >> 2;
    for (int it = 0; it < itn; ++it) {
        int idx = beg + it * 4 + grp;
        bool valid = idx < end;
        int s = csr[valid ? idx : beg].x;
        uint4 v = xws[(size_t)s * 16 + gl];
        float f[8];
        unpack_bf8(v, f);
        if (valid) {
            #pragma unroll
            for (int j = 0; j < 8; ++j) acc[j] += f[j];
        }
    }
    #pragma unroll
    for (int j = 0; j < 8; ++j) {
        acc[j] += __shfl_xor(acc[j], 16, 64);
        acc[j] += __shfl_xor(acc[j], 32, 64);
    }

    if (grp == 0) {
        float f[8];
        unpack_bf8(xws[(size_t)n * 16 + gl], f);
        float dn = dis[n];
        const float4* b4 = (const float4*)(bias + gl * 8);
        float4 b0 = b4[0], b1 = b4[1];
        float o[8];
        o[0] = b0.x + dn * (acc[0] + f[0]);
        o[1] = b0.y + dn * (acc[1] + f[1]);
        o[2] = b0.z + dn * (acc[2] + f[2]);
        o[3] = b0.w + dn * (acc[3] + f[3]);
        o[4] = b1.x + dn * (acc[4] + f[4]);
        o[5] = b1.y + dn * (acc[5] + f[5]);
        o[6] = b1.z + dn * (acc[6] + f[6]);
        o[7] = b1.w + dn * (acc[7] + f[7]);
        if (do_relu) {
            #pragma unroll
            for (int j = 0; j < 8; ++j) o[j] = fmaxf(o[j], 0.f);
        }
        uint4 pk;
        pk.x = pack_bf2(o[0], o[1]);
        pk.y = pack_bf2(o[2], o[3]);
        pk.z = pack_bf2(o[4], o[5]);
        pk.w = pack_bf2(o[6], o[7]);
        out[(size_t)n * 16 + gl] = pk;
    }
}

// MFMA GEMM: out[N][CT*16] (bf16) = (A[N][128]_bf16 @ B) epilogue (+bias for ct<bias_ct, *rowscale)
// B pre-converted to fragment order. No LDS, no barriers. Block = 4 waves = 64 rows.
__launch_bounds__(256)
__global__ void mfma_gemm(const uint4* __restrict__ A, const uint4* __restrict__ Bf,
                          const float* __restrict__ bias, const float* __restrict__ rowscale,
                          unsigned short* __restrict__ out, int N, int CT, int bias_ct) {
    int wave = threadIdx.x >> 6, lane = threadIdx.x & 63;
    int rbase = (blockIdx.x * 4 + wave) * 16;
    if (rbase >= N) return;
    int quad = lane >> 4, gl = lane & 15;
    int r = rbase + gl;
    if (r >= N) r = N - 1;

    bf16x8 afr[4];
    #pragma unroll
    for (int kk = 0; kk < 4; ++kk)
        afr[kk] = *(const bf16x8*)&A[(size_t)r * 16 + kk * 4 + quad];

    float rs[4];
    #pragma unroll
    for (int reg = 0; reg < 4; ++reg) {
        int row = rbase + quad * 4 + reg;
        rs[reg] = (rowscale && row < N) ? rowscale[row] : 1.f;
    }

    int ncols = CT * 16;
    for (int c = 0; c < CT; ++c) {
        f32x4 acc = {0.f, 0.f, 0.f, 0.f};
        #pragma unroll
        for (int kk = 0; kk < 4; ++kk) {
            bf16x8 bfr = *(const bf16x8*)&Bf[(size_t)(c * 4 + kk) * 64 + lane];
            acc = __builtin_amdgcn_mfma_f32_16x16x32_bf16(afr[kk], bfr, acc, 0, 0, 0);
        }
        float bv = (c < bias_ct) ? bias[c * 16 + gl] : 0.f;
        #pragma unroll
        for (int reg = 0; reg < 4; ++reg) {
            int row = rbase + quad * 4 + reg;
            if (row < N)
                out[(size_t)row * ncols + c * 16 + gl] = bf16r((acc[reg] + bv) * rs[reg]);
        }
    }
}

// dst-grouped edge MLP over combined HsHd[N][256] bf16 (Hs = cols 0..127, Hd = 128..255).
__global__ void edge_mlp_kernel(const uint4* __restrict__ HsHd,
                                const float4* __restrict__ ea, const int2* __restrict__ csr,
                                const int* __restrict__ rowptr,
                                const float* __restrict__ Wb, const float* __restrict__ Wm2,
                                const float* __restrict__ bm2,
                                float* __restrict__ out, int N) {
    int wave = threadIdx.x >> 6;
    int lane = threadIdx.x & 63;
    int n = blockIdx.x * (blockDim.x >> 6) + wave;
    if (n >= N) return;
    int beg = rowptr[n], end = rowptr[n + 1];
    if (beg == end) return;
    int gl = lane & 15, grp = lane >> 4;

    float hd[8];
    unpack_bf8(HsHd[(size_t)n * 32 + 16 + gl], hd);

    float wb[4][8];
    #pragma unroll
    for (int k = 0; k < 4; ++k) {
        const float4* w4 = (const float4*)(Wb + k * HID + gl * 8);
        float4 a = w4[0], b = w4[1];
        wb[k][0] = a.x; wb[k][1] = a.y; wb[k][2] = a.z; wb[k][3] = a.w;
        wb[k][4] = b.x; wb[k][5] = b.y; wb[k][6] = b.z; wb[k][7] = b.w;
    }
    float w2[8];
    {
        const float4* w4 = (const float4*)(Wm2 + gl * 8);
        float4 a = w4[0], b = w4[1];
        w2[0] = a.x; w2[1] = a.y; w2[2] = a.z; w2[3] = a.w;
        w2[4] = b.x; w2[5] = b.y; w2[6] = b.z; w2[7] = b.w;
    }
    float b2v = bm2[0];

    int itn = (end - beg + 3) >> 2;
    for (int it = 0; it < itn; ++it) {
        int idx = beg + it * 4 + grp;
        bool valid = idx < end;
        int2 ce = csr[valid ? idx : beg];
        uint4 hv = HsHd[(size_t)ce.x * 32 + gl];
        float4 eav = ea[ce.y];
        float hs[8];
        unpack_bf8(hv, hs);
        float p = 0.f;
        #pragma unroll
        for (int j = 0; j < 8; ++j) {
            float t = hs[j] + hd[j] + eav.x * wb[0][j] + eav.y * wb[1][j]
                                    + eav.z * wb[2][j] + eav.w * wb[3][j];
            t = fmaxf(t, 0.f);
            p += t * w2[j];
        }
        p += __shfl_xor(p, 1, 64);
        p += __shfl_xor(p, 2, 64);
        p += __shfl_xor(p, 4, 64);
        p += __shfl_xor(p, 8, 64);
        if (valid && gl == 0) out[ce.y] = 1.f / (1.f + expf(-(p + b2v)));
    }
}

// ---------------- launch ----------------

extern "C" void kernel_launch(void* const* d_in, const int* in_sizes, int n_in,
                              void* d_out, int out_size, void* d_ws, size_t ws_size,
                              hipStream_t stream) {
    const float* x    = (const float*)d_in[0];
    const float* ea   = (const float*)d_in[1];
    const float* W1   = (const float*)d_in[2];
    const float* b1   = (const float*)d_in[3];
    const float* W2   = (const float*)d_in[4];
    const float* b2   = (const float*)d_in[5];
    const float* Wm1  = (const float*)d_in[6];
    const float* bm1  = (const float*)d_in[7];
    const float* Wm2  = (const float*)d_in[8];
    const float* bm2  = (const float*)d_in[9];
    const int*   ei   = (const int*)d_in[10];

    const int N = in_sizes[0] / 5;
    const int E = in_sizes[1] / 4;
    const int* src = ei;
    const int* dst = ei + E;
    float* out = (float*)d_out;

    char* ws = (char*)d_ws;
    size_t off = 0;
    auto alloc = [&](size_t bytes) -> void* {
        void* p = ws + off;
        off = (off + bytes + 255) & ~(size_t)255;
        return p;
    };
    int*   cnt    = (int*)alloc((size_t)N * 4);
    int*   rowptr = (int*)alloc((size_t)(N + 1) * 4);
    int*   cursor = (int*)alloc((size_t)N * 4);
    int*   bsum   = (int*)alloc(256 * 4);
    float* dis    = (float*)alloc((size_t)N * 4);
    int2*  csr    = (int2*)alloc((size_t)E * 8);
    // R1: 25.6 MB — holds xws1/xws2 (first half) early, HsHd (full) late
    uint*  R1     = (uint*)alloc((size_t)N * 128 * 2);
    uint*  hbuf   = (uint*)alloc((size_t)N * 64 * 4);    // bf16 h1 -> h
    uint*  fW2    = (uint*)alloc(8192 * 4);
    uint*  fWm1   = (uint*)alloc(16384 * 4);
    (void)ws_size; (void)n_in; (void)out_size;

    uint* xws  = R1;        // [N][64] uint (bf16 x 128)
    uint* HsHd = R1;        // [N][128] uint (bf16 x 256)

    const int NB = (N + 255) / 256;
    const int EB = (E + 255) / 256;

    // weight frag prep (independent)
    prep_frags<<<(24576 + 255) / 256, 256, 0, stream>>>(W2, Wm1, fW2, fWm1);

    // CSR build
    zero_int<<<NB, 256, 0, stream>>>(cnt, N);
    hist_kernel<<<EB, 256, 0, stream>>>(dst, cnt, E);
    scan1<<<NB, 256, 0, stream>>>(cnt, rowptr, bsum, N);
    scan2<<<1, 256, 0, stream>>>(bsum, NB);
    scan3<<<NB, 256, 0, stream>>>(cnt, rowptr, bsum, cursor, dis, N, E);
    scatter_kernel<<<EB, 256, 0, stream>>>(src, dst, cursor, csr, E);

    // GCN layer 1: xws1 = dis*(x@W1); h1 = relu(b1 + dis*agg(xws1))
    xw1_kernel<<<(N * 64 + 255) / 256, 256, 0, stream>>>(x, W1, dis, xws, N);
    aggregate_kernel<<<(N + 3) / 4, 256, 0, stream>>>((const uint4*)xws, csr, rowptr, dis,
                                                      b1, (uint4*)hbuf, N, 1);

    // GCN layer 2: xws2 = dis*(h1@W2) [MFMA]; h = b2 + dis*agg(xws2)
    mfma_gemm<<<(N + 63) / 64, 256, 0, stream>>>((const uint4*)hbuf, (const uint4*)fW2,
                                                 b1 /*unused*/, dis,
                                                 (unsigned short*)xws, N, 8, 0);
    aggregate_kernel<<<(N + 3) / 4, 256, 0, stream>>>((const uint4*)xws, csr, rowptr, dis,
                                                      b2, (uint4*)hbuf, N, 0);

    // edge MLP head: HsHd = h @ [Wm1_top | Wm1_mid]  (+bm1 on first 128 cols) [MFMA]
    mfma_gemm<<<(N + 63) / 64, 256, 0, stream>>>((const uint4*)hbuf, (const uint4*)fWm1,
                                                 bm1, nullptr,
                                                 (unsigned short*)HsHd, N, 16, 8);

    // per-edge MLP + sigmoid, dst-grouped via CSR
    edge_mlp_kernel<<<(N + 3) / 4, 256, 0, stream>>>((const uint4*)HsHd,
                                                     (const float4*)ea, csr, rowptr,
                                                     Wm1 + 256 * HID, Wm2, bm2, out, N);
}

// Round 5
// 334.955 us; speedup vs baseline: 1.7847x; 1.1269x over previous
//
#include <hip/hip_runtime.h>
#include <math.h>

#define HID 128
typedef unsigned int uint;
typedef __attribute__((ext_vector_type(8))) __bf16 bf16x8;
typedef __attribute__((ext_vector_type(4))) float f32x4;
typedef __attribute__((ext_vector_type(2))) float f32x2;

// ---------------- bf16 helpers (RNE) ----------------

__device__ __forceinline__ uint pack_bf2(float x, float y) {
    union { float f; uint u; } a, b;
    a.f = x; b.f = y;
    uint lo = (a.u + 0x7fffu + ((a.u >> 16) & 1u)) >> 16;
    uint hi = (b.u + 0x7fffu + ((b.u >> 16) & 1u)) & 0xffff0000u;
    return lo | hi;
}

__device__ __forceinline__ unsigned short bf16r(float x) {
    union { float f; uint u; } a; a.f = x;
    return (unsigned short)((a.u + 0x7fffu + ((a.u >> 16) & 1u)) >> 16);
}

// one packed uint (2 bf16) -> f32x2 {even, odd}
__device__ __forceinline__ f32x2 bf2f(uint v) {
    union { uint u[2]; f32x2 f; } r;
    r.u[0] = v << 16;
    r.u[1] = v & 0xffff0000u;
    return r.f;
}

__device__ __forceinline__ f32x2 mk2(float s) { f32x2 r; r.x = s; r.y = s; return r; }
__device__ __forceinline__ f32x2 max2z(f32x2 a) {
    f32x2 r; r.x = fmaxf(a.x, 0.f); r.y = fmaxf(a.y, 0.f); return r;
}
__device__ __forceinline__ f32x2 shfl_xor2(f32x2 v, int m) {
    f32x2 r; r.x = __shfl_xor(v.x, m, 64); r.y = __shfl_xor(v.y, m, 64); return r;
}

// ---------------- setup kernels ----------------

// zero cnt + weight-fragment prep (independent work, one launch)
// frag element for (ct, kk, lane, j): B[k = kk*32 + (lane>>4)*8 + j][n = ct*16 + (lane&15)]
__global__ void zero_prep(int* __restrict__ cnt, int N,
                          const float* __restrict__ W2, const float* __restrict__ Wm1,
                          uint* __restrict__ fW2, uint* __restrict__ fWm1) {
    int stride = gridDim.x * blockDim.x;
    int t0 = blockIdx.x * blockDim.x + threadIdx.x;
    for (int i = t0; i < N; i += stride) cnt[i] = 0;
    for (int idx = t0; idx < 24576; idx += stride) {
        if (idx < 8192) {          // fW2: 8 ct
            int p = idx & 3;
            int lane = (idx >> 2) & 63;
            int kk = (idx >> 8) & 3;
            int ct = idx >> 10;
            int k = kk * 32 + (lane >> 4) * 8 + p * 2;
            int n = ct * 16 + (lane & 15);
            fW2[idx] = pack_bf2(W2[k * HID + n], W2[(k + 1) * HID + n]);
        } else {                   // fWm1: 16 ct (cols 0..127 Hs | 128..255 Hd)
            int i = idx - 8192;
            int p = i & 3;
            int lane = (i >> 2) & 63;
            int kk = (i >> 8) & 3;
            int ct = i >> 10;
            int k = kk * 32 + (lane >> 4) * 8 + p * 2;
            int n = ct * 16 + (lane & 15);
            float v0, v1;
            if (n < 128) { v0 = Wm1[k * HID + n];               v1 = Wm1[(k + 1) * HID + n]; }
            else         { v0 = Wm1[(128 + k) * HID + n - 128]; v1 = Wm1[(129 + k) * HID + n - 128]; }
            fWm1[i] = pack_bf2(v0, v1);
        }
    }
}

__global__ void hist_kernel(const int* __restrict__ dst, int* __restrict__ cnt, int E) {
    int e = blockIdx.x * blockDim.x + threadIdx.x;
    if (e < E) atomicAdd(&cnt[dst[e]], 1);
}

// per-chunk exclusive scan of cnt, chunk sums to bsum
__global__ void scan1(const int* __restrict__ cnt, int* __restrict__ excl,
                      int* __restrict__ bsum, int N) {
    __shared__ int sh[256];
    int tid = threadIdx.x;
    int gid = blockIdx.x * 256 + tid;
    int v = (gid < N) ? cnt[gid] : 0;
    sh[tid] = v;
    __syncthreads();
    for (int o = 1; o < 256; o <<= 1) {
        int t = (tid >= o) ? sh[tid - o] : 0;
        __syncthreads();
        sh[tid] += t;
        __syncthreads();
    }
    if (gid < N) excl[gid] = sh[tid] - v;
    if (tid == 255) bsum[blockIdx.x] = sh[255];
}

// fused: every block redundantly scans bsum (<=256 entries) in LDS, then finalizes
// rowptr/cursor/dis for its chunk.  (replaces scan2+scan3)
__global__ void scan3x(const int* __restrict__ cnt, int* __restrict__ rowptr,
                       const int* __restrict__ bsum, int* __restrict__ cursor,
                       float* __restrict__ dis, int N, int E, int NB) {
    __shared__ int sh[256];
    __shared__ int ex[256];
    int tid = threadIdx.x;
    int v = (tid < NB) ? bsum[tid] : 0;
    sh[tid] = v;
    __syncthreads();
    for (int o = 1; o < 256; o <<= 1) {
        int t = (tid >= o) ? sh[tid - o] : 0;
        __syncthreads();
        sh[tid] += t;
        __syncthreads();
    }
    ex[tid] = sh[tid] - v;
    __syncthreads();
    int gid = blockIdx.x * 256 + tid;
    if (gid < N) {
        int r = rowptr[gid] + ex[blockIdx.x];
        rowptr[gid] = r;
        cursor[gid] = r;
        dis[gid] = rsqrtf((float)cnt[gid] + 1.0f);   // deg incl. self-loop
    }
    if (gid == N) rowptr[N] = E;
}

// fused scatter (csr int4 = src,dst,eid,0) + xw1 (xws1 = dis*(x@W1), bf16)
__global__ void scatter_xw1(const int* __restrict__ src, const int* __restrict__ dst,
                            int* __restrict__ cursor, int4* __restrict__ csr, int E,
                            const float* __restrict__ x, const float* __restrict__ W1,
                            const float* __restrict__ dis, uint* __restrict__ xws, int N) {
    int stride = gridDim.x * blockDim.x;
    int t0 = blockIdx.x * blockDim.x + threadIdx.x;
    for (int e = t0; e < E; e += stride) {
        int d = dst[e];
        int pos = atomicAdd(&cursor[d], 1);
        csr[pos] = make_int4(src[e], d, e, 0);
    }
    for (int idx = t0; idx < N * 64; idx += stride) {
        int n = idx >> 6, p = idx & 63;
        int j = p * 2;
        const float* xr = x + n * 5;
        float a0 = 0.f, a1 = 0.f;
        #pragma unroll
        for (int k = 0; k < 5; ++k) {
            a0 += xr[k] * W1[k * HID + j];
            a1 += xr[k] * W1[k * HID + j + 1];
        }
        float dn = dis[n];
        xws[idx] = pack_bf2(a0 * dn, a1 * dn);
    }
}

// ---------------- hot kernels ----------------

// GCN aggregation: out[n] = bias + dis[n]*( sum_{in(n)} xws[s] + xws[n] ), bf16 out.
// wave per node; 16-lane group per edge; 8 edges/iter (2 per group) with src prefetch.
__global__ void aggregate_kernel(const uint4* __restrict__ xws, const int4* __restrict__ csr,
                                 const int* __restrict__ rowptr, const float* __restrict__ dis,
                                 const float* __restrict__ bias, uint4* __restrict__ out,
                                 int N, int do_relu) {
    int wave = threadIdx.x >> 6;
    int lane = threadIdx.x & 63;
    int n = blockIdx.x * (blockDim.x >> 6) + wave;
    if (n >= N) return;
    int gl = lane & 15, grp = lane >> 4;
    int beg = rowptr[n], end = rowptr[n + 1];

    f32x2 acc[4];
    #pragma unroll
    for (int p = 0; p < 4; ++p) acc[p] = mk2(0.f);

    if (beg < end) {
        int i0 = beg + grp;
        int i1 = i0 + 4;
        int s0 = csr[(i0 < end) ? i0 : beg].x;
        int s1 = csr[(i1 < end) ? i1 : beg].x;
        for (int it = i0; it < end; it += 8) {
            // issue current rows
            uint4 v0 = xws[(size_t)s0 * 16 + gl];
            uint4 v1 = xws[(size_t)s1 * 16 + gl];
            // prefetch next srcs (independent of v0/v1)
            int n0 = it + 8, n1 = it + 12;
            int t0 = csr[(n0 < end) ? n0 : beg].x;
            int t1 = csr[(n1 < end) ? n1 : beg].x;
            float w1 = (it + 4 < end) ? 1.f : 0.f;
            f32x2 w1v = mk2(w1);
            acc[0] += bf2f(v0.x);  acc[0] += bf2f(v1.x) * w1v;
            acc[1] += bf2f(v0.y);  acc[1] += bf2f(v1.y) * w1v;
            acc[2] += bf2f(v0.z);  acc[2] += bf2f(v1.z) * w1v;
            acc[3] += bf2f(v0.w);  acc[3] += bf2f(v1.w) * w1v;
            s0 = t0; s1 = t1;
        }
    }
    #pragma unroll
    for (int p = 0; p < 4; ++p) {
        acc[p] += shfl_xor2(acc[p], 16);
        acc[p] += shfl_xor2(acc[p], 32);
    }

    if (grp == 0) {
        uint4 sv = xws[(size_t)n * 16 + gl];
        f32x2 dn = mk2(dis[n]);
        const float* bp = bias + gl * 8;
        f32x2 o[4];
        o[0] = (acc[0] + bf2f(sv.x)) * dn + *(const f32x2*)(bp);
        o[1] = (acc[1] + bf2f(sv.y)) * dn + *(const f32x2*)(bp + 2);
        o[2] = (acc[2] + bf2f(sv.z)) * dn + *(const f32x2*)(bp + 4);
        o[3] = (acc[3] + bf2f(sv.w)) * dn + *(const f32x2*)(bp + 6);
        if (do_relu) {
            #pragma unroll
            for (int p = 0; p < 4; ++p) o[p] = max2z(o[p]);
        }
        uint4 pk;
        pk.x = pack_bf2(o[0].x, o[0].y);
        pk.y = pack_bf2(o[1].x, o[1].y);
        pk.z = pack_bf2(o[2].x, o[2].y);
        pk.w = pack_bf2(o[3].x, o[3].y);
        out[(size_t)n * 16 + gl] = pk;
    }
}

// MFMA GEMM: out[N][CT*16] (bf16) = A[N][128]_bf16 @ Bf (+bias for ct<bias_ct, *rowscale)
__launch_bounds__(256)
__global__ void mfma_gemm(const uint4* __restrict__ A, const uint4* __restrict__ Bf,
                          const float* __restrict__ bias, const float* __restrict__ rowscale,
                          unsigned short* __restrict__ out, int N, int CT, int bias_ct) {
    int wave = threadIdx.x >> 6, lane = threadIdx.x & 63;
    int rbase = (blockIdx.x * 4 + wave) * 16;
    if (rbase >= N) return;
    int quad = lane >> 4, gl = lane & 15;
    int r = rbase + gl;
    if (r >= N) r = N - 1;

    bf16x8 afr[4];
    #pragma unroll
    for (int kk = 0; kk < 4; ++kk)
        afr[kk] = *(const bf16x8*)&A[(size_t)r * 16 + kk * 4 + quad];

    float rs[4];
    #pragma unroll
    for (int reg = 0; reg < 4; ++reg) {
        int row = rbase + quad * 4 + reg;
        rs[reg] = (rowscale && row < N) ? rowscale[row] : 1.f;
    }

    int ncols = CT * 16;
    for (int c = 0; c < CT; ++c) {
        f32x4 acc = {0.f, 0.f, 0.f, 0.f};
        #pragma unroll
        for (int kk = 0; kk < 4; ++kk) {
            bf16x8 bfr = *(const bf16x8*)&Bf[(size_t)(c * 4 + kk) * 64 + lane];
            acc = __builtin_amdgcn_mfma_f32_16x16x32_bf16(afr[kk], bfr, acc, 0, 0, 0);
        }
        float bv = (c < bias_ct) ? bias[c * 16 + gl] : 0.f;
        #pragma unroll
        for (int reg = 0; reg < 4; ++reg) {
            int row = rbase + quad * 4 + reg;
            if (row < N)
                out[(size_t)row * ncols + c * 16 + gl] = bf16r((acc[reg] + bv) * rs[reg]);
        }
    }
}

// edge-parallel edge MLP over dst-sorted csr (int4 src,dst,eid).
// 16-lane group per edge, 4 edges per wave per iter; grid-stride; packed-f32 math.
__launch_bounds__(256)
__global__ void edge_mlp_kernel(const uint4* __restrict__ HsHd, const float4* __restrict__ ea,
                                const int4* __restrict__ csr,
                                const float* __restrict__ Wb, const float* __restrict__ Wm2,
                                const float* __restrict__ bm2,
                                float* __restrict__ out, int E) {
    int lane = threadIdx.x & 63;
    int gl = lane & 15, grp = lane >> 4;

    f32x2 wb[4][4], w2[4];
    #pragma unroll
    for (int k = 0; k < 4; ++k) {
        const f32x2* wp = (const f32x2*)(Wb + k * HID + gl * 8);
        #pragma unroll
        for (int p = 0; p < 4; ++p) wb[k][p] = wp[p];
    }
    {
        const f32x2* wp = (const f32x2*)(Wm2 + gl * 8);
        #pragma unroll
        for (int p = 0; p < 4; ++p) w2[p] = wp[p];
    }
    float b2v = bm2[0];

    int gwave = (blockIdx.x * blockDim.x + threadIdx.x) >> 6;
    int nw = (gridDim.x * blockDim.x) >> 6;
    for (int base = gwave * 4; base < E; base += nw * 4) {
        int i = base + grp;
        int4 ce = csr[(i < E) ? i : (E - 1)];
        uint4 hv = HsHd[(size_t)ce.x * 32 + gl];        // Hs[src]
        uint4 dv = HsHd[(size_t)ce.y * 32 + 16 + gl];   // Hd[dst] (L1-hot in dst runs)
        float4 eav = ea[ce.z];
        f32x2 e0 = mk2(eav.x), e1 = mk2(eav.y), e2 = mk2(eav.z), e3 = mk2(eav.w);
        f32x2 p2 = mk2(0.f);
        uint hu[4] = {hv.x, hv.y, hv.z, hv.w};
        uint du[4] = {dv.x, dv.y, dv.z, dv.w};
        #pragma unroll
        for (int p = 0; p < 4; ++p) {
            f32x2 t = bf2f(hu[p]) + bf2f(du[p]);
            t += e0 * wb[0][p];
            t += e1 * wb[1][p];
            t += e2 * wb[2][p];
            t += e3 * wb[3][p];
            t = max2z(t);
            p2 += t * w2[p];
        }
        float p = p2.x + p2.y;
        p += __shfl_xor(p, 1, 64);
        p += __shfl_xor(p, 2, 64);
        p += __shfl_xor(p, 4, 64);
        p += __shfl_xor(p, 8, 64);
        if (gl == 0 && i < E) out[ce.z] = 1.f / (1.f + expf(-(p + b2v)));
    }
}

// ---------------- launch ----------------

extern "C" void kernel_launch(void* const* d_in, const int* in_sizes, int n_in,
                              void* d_out, int out_size, void* d_ws, size_t ws_size,
                              hipStream_t stream) {
    const float* x    = (const float*)d_in[0];
    const float* ea   = (const float*)d_in[1];
    const float* W1   = (const float*)d_in[2];
    const float* b1   = (const float*)d_in[3];
    const float* W2   = (const float*)d_in[4];
    const float* b2   = (const float*)d_in[5];
    const float* Wm1  = (const float*)d_in[6];
    const float* bm1  = (const float*)d_in[7];
    const float* Wm2  = (const float*)d_in[8];
    const float* bm2  = (const float*)d_in[9];
    const int*   ei   = (const int*)d_in[10];

    const int N = in_sizes[0] / 5;
    const int E = in_sizes[1] / 4;
    const int* src = ei;
    const int* dst = ei + E;
    float* out = (float*)d_out;

    char* ws = (char*)d_ws;
    size_t off = 0;
    auto alloc = [&](size_t bytes) -> void* {
        void* p = ws + off;
        off = (off + bytes + 255) & ~(size_t)255;
        return p;
    };
    int*   cnt    = (int*)alloc((size_t)N * 4);
    int*   rowptr = (int*)alloc((size_t)(N + 1) * 4);
    int*   cursor = (int*)alloc((size_t)N * 4);
    int*   bsum   = (int*)alloc(256 * 4);
    float* dis    = (float*)alloc((size_t)N * 4);
    int4*  csr    = (int4*)alloc((size_t)(E + 8) * 16);
    uint*  R1     = (uint*)alloc((size_t)N * 128 * 4);  // FIXED size: full HsHd [N][256] bf16
    uint*  hbuf   = (uint*)alloc((size_t)N * 64 * 4);   // bf16 h1 -> h
    uint*  fW2    = (uint*)alloc(8192 * 4);
    uint*  fWm1   = (uint*)alloc(16384 * 4);
    (void)ws_size; (void)n_in; (void)out_size;

    uint* xws  = R1;        // [N][64] uint (bf16 x 128)
    uint* HsHd = R1;        // [N][128] uint (bf16 x 256)

    const int NB = (N + 255) / 256;
    const int EB = (E + 255) / 256;

    // setup: zero cnt + weight frags
    zero_prep<<<NB, 256, 0, stream>>>(cnt, N, W2, Wm1, fW2, fWm1);
    hist_kernel<<<EB, 256, 0, stream>>>(dst, cnt, E);
    scan1<<<NB, 256, 0, stream>>>(cnt, rowptr, bsum, N);
    scan3x<<<NB, 256, 0, stream>>>(cnt, rowptr, bsum, cursor, dis, N, E, NB);
    scatter_xw1<<<EB, 256, 0, stream>>>(src, dst, cursor, csr, E, x, W1, dis, xws, N);

    // GCN layer 1: h1 = relu(b1 + dis*agg(xws1))
    aggregate_kernel<<<(N + 3) / 4, 256, 0, stream>>>((const uint4*)xws, csr, rowptr, dis,
                                                      b1, (uint4*)hbuf, N, 1);
    // GCN layer 2: xws2 = dis*(h1@W2) [MFMA]; h = b2 + dis*agg(xws2)
    mfma_gemm<<<(N + 63) / 64, 256, 0, stream>>>((const uint4*)hbuf, (const uint4*)fW2,
                                                 b1 /*unused*/, dis,
                                                 (unsigned short*)xws, N, 8, 0);
    aggregate_kernel<<<(N + 3) / 4, 256, 0, stream>>>((const uint4*)xws, csr, rowptr, dis,
                                                      b2, (uint4*)hbuf, N, 0);
    // edge MLP head: HsHd = h @ [Wm1_top | Wm1_mid] (+bm1 on first 128 cols) [MFMA]
    mfma_gemm<<<(N + 63) / 64, 256, 0, stream>>>((const uint4*)hbuf, (const uint4*)fWm1,
                                                 bm1, nullptr,
                                                 (unsigned short*)HsHd, N, 16, 8);
    // per-edge MLP + sigmoid, edge-parallel over dst-sorted csr
    edge_mlp_kernel<<<3072, 256, 0, stream>>>((const uint4*)HsHd, (const float4*)ea, csr,
                                              Wm1 + 256 * HID, Wm2, bm2, out, E);
}

// Round 6
// 325.141 us; speedup vs baseline: 1.8386x; 1.0302x over previous
//
#include <hip/hip_runtime.h>
#include <math.h>

#define HID 128
typedef unsigned int uint;
typedef __attribute__((ext_vector_type(8))) __bf16 bf16x8;
typedef __attribute__((ext_vector_type(4))) float f32x4;
typedef __attribute__((ext_vector_type(2))) float f32x2;

// ---------------- bf16 helpers (RNE) ----------------

__device__ __forceinline__ uint pack_bf2(float x, float y) {
    union { float f; uint u; } a, b;
    a.f = x; b.f = y;
    uint lo = (a.u + 0x7fffu + ((a.u >> 16) & 1u)) >> 16;
    uint hi = (b.u + 0x7fffu + ((b.u >> 16) & 1u)) & 0xffff0000u;
    return lo | hi;
}

__device__ __forceinline__ unsigned short bf16r(float x) {
    union { float f; uint u; } a; a.f = x;
    return (unsigned short)((a.u + 0x7fffu + ((a.u >> 16) & 1u)) >> 16);
}

// one packed uint (2 bf16) -> f32x2 {even, odd}
__device__ __forceinline__ f32x2 bf2f(uint v) {
    union { uint u[2]; f32x2 f; } r;
    r.u[0] = v << 16;
    r.u[1] = v & 0xffff0000u;
    return r.f;
}

__device__ __forceinline__ f32x2 mk2(float s) { f32x2 r; r.x = s; r.y = s; return r; }
__device__ __forceinline__ f32x2 max2z(f32x2 a) {
    f32x2 r; r.x = fmaxf(a.x, 0.f); r.y = fmaxf(a.y, 0.f); return r;
}
__device__ __forceinline__ f32x2 shfl_xor2(f32x2 v, int m) {
    f32x2 r; r.x = __shfl_xor(v.x, m, 64); r.y = __shfl_xor(v.y, m, 64); return r;
}

// ---------------- setup kernels ----------------

// zero cnt + weight-fragment prep
// frag element for (ct, kk, lane, j): B[k = kk*32 + (lane>>4)*8 + j][n = ct*16 + (lane&15)]
__global__ void zero_prep(int* __restrict__ cnt, int N,
                          const float* __restrict__ W2, const float* __restrict__ Wm1,
                          uint* __restrict__ fW2, uint* __restrict__ fWm1) {
    int stride = gridDim.x * blockDim.x;
    int t0 = blockIdx.x * blockDim.x + threadIdx.x;
    for (int i = t0; i < N; i += stride) cnt[i] = 0;
    for (int idx = t0; idx < 24576; idx += stride) {
        if (idx < 8192) {          // fW2: 8 ct
            int p = idx & 3;
            int lane = (idx >> 2) & 63;
            int kk = (idx >> 8) & 3;
            int ct = idx >> 10;
            int k = kk * 32 + (lane >> 4) * 8 + p * 2;
            int n = ct * 16 + (lane & 15);
            fW2[idx] = pack_bf2(W2[k * HID + n], W2[(k + 1) * HID + n]);
        } else {                   // fWm1: 16 ct (cols 0..127 Hs | 128..255 Hd)
            int i = idx - 8192;
            int p = i & 3;
            int lane = (i >> 2) & 63;
            int kk = (i >> 8) & 3;
            int ct = i >> 10;
            int k = kk * 32 + (lane >> 4) * 8 + p * 2;
            int n = ct * 16 + (lane & 15);
            float v0, v1;
            if (n < 128) { v0 = Wm1[k * HID + n];               v1 = Wm1[(k + 1) * HID + n]; }
            else         { v0 = Wm1[(128 + k) * HID + n - 128]; v1 = Wm1[(129 + k) * HID + n - 128]; }
            fWm1[i] = pack_bf2(v0, v1);
        }
    }
}

__global__ void hist_kernel(const int* __restrict__ dst, int* __restrict__ cnt, int E) {
    int e = blockIdx.x * blockDim.x + threadIdx.x;
    if (e < E) atomicAdd(&cnt[dst[e]], 1);
}

__global__ void scan1(const int* __restrict__ cnt, int* __restrict__ excl,
                      int* __restrict__ bsum, int N) {
    __shared__ int sh[256];
    int tid = threadIdx.x;
    int gid = blockIdx.x * 256 + tid;
    int v = (gid < N) ? cnt[gid] : 0;
    sh[tid] = v;
    __syncthreads();
    for (int o = 1; o < 256; o <<= 1) {
        int t = (tid >= o) ? sh[tid - o] : 0;
        __syncthreads();
        sh[tid] += t;
        __syncthreads();
    }
    if (gid < N) excl[gid] = sh[tid] - v;
    if (tid == 255) bsum[blockIdx.x] = sh[255];
}

// every block redundantly scans bsum (<=256 entries) in LDS, then finalizes its chunk
__global__ void scan3x(const int* __restrict__ cnt, int* __restrict__ rowptr,
                       const int* __restrict__ bsum, int* __restrict__ cursor,
                       float* __restrict__ dis, int N, int E, int NB) {
    __shared__ int sh[256];
    __shared__ int ex[256];
    int tid = threadIdx.x;
    int v = (tid < NB) ? bsum[tid] : 0;
    sh[tid] = v;
    __syncthreads();
    for (int o = 1; o < 256; o <<= 1) {
        int t = (tid >= o) ? sh[tid - o] : 0;
        __syncthreads();
        sh[tid] += t;
        __syncthreads();
    }
    ex[tid] = sh[tid] - v;
    __syncthreads();
    int gid = blockIdx.x * 256 + tid;
    if (gid < N) {
        int r = rowptr[gid] + ex[blockIdx.x];
        rowptr[gid] = r;
        cursor[gid] = r;
        dis[gid] = rsqrtf((float)cnt[gid] + 1.0f);   // deg incl. self-loop
    }
    if (gid == N) rowptr[N] = E;
}

// fused scatter (csr int4 = src,dst,eid,0; csrc = src only) + xw1 (xws1 = dis*(x@W1), bf16)
__global__ void scatter_xw1(const int* __restrict__ src, const int* __restrict__ dst,
                            int* __restrict__ cursor, int4* __restrict__ csr,
                            int* __restrict__ csrc, int E,
                            const float* __restrict__ x, const float* __restrict__ W1,
                            const float* __restrict__ dis, uint* __restrict__ xws, int N) {
    int stride = gridDim.x * blockDim.x;
    int t0 = blockIdx.x * blockDim.x + threadIdx.x;
    for (int e = t0; e < E; e += stride) {
        int d = dst[e];
        int s = src[e];
        int pos = atomicAdd(&cursor[d], 1);
        csr[pos] = make_int4(s, d, e, 0);
        csrc[pos] = s;
    }
    for (int idx = t0; idx < N * 64; idx += stride) {
        int n = idx >> 6, p = idx & 63;
        int j = p * 2;
        const float* xr = x + n * 5;
        float a0 = 0.f, a1 = 0.f;
        #pragma unroll
        for (int k = 0; k < 5; ++k) {
            a0 += xr[k] * W1[k * HID + j];
            a1 += xr[k] * W1[k * HID + j + 1];
        }
        float dn = dis[n];
        xws[idx] = pack_bf2(a0 * dn, a1 * dn);
    }
}

// ---------------- hot kernels ----------------

// GCN aggregation: out[n] = bias + dis[n]*( sum_{in(n)} xws[s] + xws[n] ), bf16 out.
// wave per node; 16-lane group per edge; 4-deep unroll => 16 edges in flight per wave.
__global__ void aggregate_kernel(const uint4* __restrict__ xws, const int* __restrict__ csrc,
                                 const int* __restrict__ rowptr, const float* __restrict__ dis,
                                 const float* __restrict__ bias, uint4* __restrict__ out,
                                 int N, int do_relu) {
    int wave = threadIdx.x >> 6;
    int lane = threadIdx.x & 63;
    int n = blockIdx.x * (blockDim.x >> 6) + wave;
    if (n >= N) return;
    int gl = lane & 15, grp = lane >> 4;
    int beg = rowptr[n], end = rowptr[n + 1];

    f32x2 acc[4];
    #pragma unroll
    for (int p = 0; p < 4; ++p) acc[p] = mk2(0.f);

    for (int base = beg + grp; base < end; base += 16) {
        int i1 = base + 4, i2 = base + 8, i3 = base + 12;
        int s0 = csrc[base];
        int s1 = csrc[(i1 < end) ? i1 : beg];
        int s2 = csrc[(i2 < end) ? i2 : beg];
        int s3 = csrc[(i3 < end) ? i3 : beg];
        uint4 v0 = xws[(size_t)s0 * 16 + gl];
        uint4 v1 = xws[(size_t)s1 * 16 + gl];
        uint4 v2 = xws[(size_t)s2 * 16 + gl];
        uint4 v3 = xws[(size_t)s3 * 16 + gl];
        f32x2 w1 = mk2((i1 < end) ? 1.f : 0.f);
        f32x2 w2 = mk2((i2 < end) ? 1.f : 0.f);
        f32x2 w3 = mk2((i3 < end) ? 1.f : 0.f);
        acc[0] += bf2f(v0.x);  acc[1] += bf2f(v0.y);
        acc[2] += bf2f(v0.z);  acc[3] += bf2f(v0.w);
        acc[0] += bf2f(v1.x) * w1;  acc[1] += bf2f(v1.y) * w1;
        acc[2] += bf2f(v1.z) * w1;  acc[3] += bf2f(v1.w) * w1;
        acc[0] += bf2f(v2.x) * w2;  acc[1] += bf2f(v2.y) * w2;
        acc[2] += bf2f(v2.z) * w2;  acc[3] += bf2f(v2.w) * w2;
        acc[0] += bf2f(v3.x) * w3;  acc[1] += bf2f(v3.y) * w3;
        acc[2] += bf2f(v3.z) * w3;  acc[3] += bf2f(v3.w) * w3;
    }
    #pragma unroll
    for (int p = 0; p < 4; ++p) {
        acc[p] += shfl_xor2(acc[p], 16);
        acc[p] += shfl_xor2(acc[p], 32);
    }

    if (grp == 0) {
        uint4 sv = xws[(size_t)n * 16 + gl];
        f32x2 dn = mk2(dis[n]);
        const float* bp = bias + gl * 8;
        f32x2 o[4];
        o[0] = (acc[0] + bf2f(sv.x)) * dn + *(const f32x2*)(bp);
        o[1] = (acc[1] + bf2f(sv.y)) * dn + *(const f32x2*)(bp + 2);
        o[2] = (acc[2] + bf2f(sv.z)) * dn + *(const f32x2*)(bp + 4);
        o[3] = (acc[3] + bf2f(sv.w)) * dn + *(const f32x2*)(bp + 6);
        if (do_relu) {
            #pragma unroll
            for (int p = 0; p < 4; ++p) o[p] = max2z(o[p]);
        }
        uint4 pk;
        pk.x = pack_bf2(o[0].x, o[0].y);
        pk.y = pack_bf2(o[1].x, o[1].y);
        pk.z = pack_bf2(o[2].x, o[2].y);
        pk.w = pack_bf2(o[3].x, o[3].y);
        out[(size_t)n * 16 + gl] = pk;
    }
}

// MFMA GEMM: out[N][CT*16] (bf16) = A[N][128]_bf16 @ Bf (+bias for ct<bias_ct, *rowscale)
__launch_bounds__(256)
__global__ void mfma_gemm(const uint4* __restrict__ A, const uint4* __restrict__ Bf,
                          const float* __restrict__ bias, const float* __restrict__ rowscale,
                          unsigned short* __restrict__ out, int N, int CT, int bias_ct) {
    int wave = threadIdx.x >> 6, lane = threadIdx.x & 63;
    int rbase = (blockIdx.x * 4 + wave) * 16;
    if (rbase >= N) return;
    int quad = lane >> 4, gl = lane & 15;
    int r = rbase + gl;
    if (r >= N) r = N - 1;

    bf16x8 afr[4];
    #pragma unroll
    for (int kk = 0; kk < 4; ++kk)
        afr[kk] = *(const bf16x8*)&A[(size_t)r * 16 + kk * 4 + quad];

    float rs[4];
    #pragma unroll
    for (int reg = 0; reg < 4; ++reg) {
        int row = rbase + quad * 4 + reg;
        rs[reg] = (rowscale && row < N) ? rowscale[row] : 1.f;
    }

    int ncols = CT * 16;
    for (int c = 0; c < CT; ++c) {
        f32x4 acc = {0.f, 0.f, 0.f, 0.f};
        #pragma unroll
        for (int kk = 0; kk < 4; ++kk) {
            bf16x8 bfr = *(const bf16x8*)&Bf[(size_t)(c * 4 + kk) * 64 + lane];
            acc = __builtin_amdgcn_mfma_f32_16x16x32_bf16(afr[kk], bfr, acc, 0, 0, 0);
        }
        float bv = (c < bias_ct) ? bias[c * 16 + gl] : 0.f;
        #pragma unroll
        for (int reg = 0; reg < 4; ++reg) {
            int row = rbase + quad * 4 + reg;
            if (row < N)
                out[(size_t)row * ncols + c * 16 + gl] = bf16r((acc[reg] + bv) * rs[reg]);
        }
    }
}

// edge-parallel edge MLP, 2-deep: 16-lane group processes 2 edges/iter (8 per wave),
// all gathers issued before use; two independent shuffle-reduce chains.
__launch_bounds__(256)
__global__ void edge_mlp_kernel(const uint4* __restrict__ HsHd, const float4* __restrict__ ea,
                                const int4* __restrict__ csr,
                                const float* __restrict__ Wb, const float* __restrict__ Wm2,
                                const float* __restrict__ bm2,
                                float* __restrict__ out, int E) {
    int lane = threadIdx.x & 63;
    int gl = lane & 15, grp = lane >> 4;

    f32x2 wb[4][4], w2[4];
    #pragma unroll
    for (int k = 0; k < 4; ++k) {
        const f32x2* wp = (const f32x2*)(Wb + k * HID + gl * 8);
        #pragma unroll
        for (int p = 0; p < 4; ++p) wb[k][p] = wp[p];
    }
    {
        const f32x2* wp = (const f32x2*)(Wm2 + gl * 8);
        #pragma unroll
        for (int p = 0; p < 4; ++p) w2[p] = wp[p];
    }
    float b2v = bm2[0];

    int gwave = (blockIdx.x * blockDim.x + threadIdx.x) >> 6;
    int nw = (gridDim.x * blockDim.x) >> 6;
    for (int base = gwave * 8; base < E; base += nw * 8) {
        int i0 = base + grp;
        int i1 = i0 + 4;
        int4 ce0 = csr[(i0 < E) ? i0 : (E - 1)];
        int4 ce1 = csr[(i1 < E) ? i1 : (E - 1)];
        uint4 hv0 = HsHd[(size_t)ce0.x * 32 + gl];
        uint4 dv0 = HsHd[(size_t)ce0.y * 32 + 16 + gl];
        uint4 hv1 = HsHd[(size_t)ce1.x * 32 + gl];
        uint4 dv1 = HsHd[(size_t)ce1.y * 32 + 16 + gl];
        float4 ea0 = ea[ce0.z];
        float4 ea1 = ea[ce1.z];

        uint hu0[4] = {hv0.x, hv0.y, hv0.z, hv0.w};
        uint du0[4] = {dv0.x, dv0.y, dv0.z, dv0.w};
        uint hu1[4] = {hv1.x, hv1.y, hv1.z, hv1.w};
        uint du1[4] = {dv1.x, dv1.y, dv1.z, dv1.w};

        f32x2 p20 = mk2(0.f), p21 = mk2(0.f);
        f32x2 a0 = mk2(ea0.x), b0 = mk2(ea0.y), c0 = mk2(ea0.z), d0 = mk2(ea0.w);
        f32x2 a1 = mk2(ea1.x), b1 = mk2(ea1.y), c1 = mk2(ea1.z), d1 = mk2(ea1.w);
        #pragma unroll
        for (int p = 0; p < 4; ++p) {
            f32x2 t0 = bf2f(hu0[p]) + bf2f(du0[p]);
            t0 += a0 * wb[0][p];
            t0 += b0 * wb[1][p];
            t0 += c0 * wb[2][p];
            t0 += d0 * wb[3][p];
            t0 = max2z(t0);
            p20 += t0 * w2[p];
            f32x2 t1 = bf2f(hu1[p]) + bf2f(du1[p]);
            t1 += a1 * wb[0][p];
            t1 += b1 * wb[1][p];
            t1 += c1 * wb[2][p];
            t1 += d1 * wb[3][p];
            t1 = max2z(t1);
            p21 += t1 * w2[p];
        }
        float p0 = p20.x + p20.y;
        float p1 = p21.x + p21.y;
        p0 += __shfl_xor(p0, 1, 64);   p1 += __shfl_xor(p1, 1, 64);
        p0 += __shfl_xor(p0, 2, 64);   p1 += __shfl_xor(p1, 2, 64);
        p0 += __shfl_xor(p0, 4, 64);   p1 += __shfl_xor(p1, 4, 64);
        p0 += __shfl_xor(p0, 8, 64);   p1 += __shfl_xor(p1, 8, 64);
        if (gl == 0 && i0 < E) out[ce0.z] = 1.f / (1.f + expf(-(p0 + b2v)));
        if (gl == 0 && i1 < E) out[ce1.z] = 1.f / (1.f + expf(-(p1 + b2v)));
    }
}

// ---------------- launch ----------------

extern "C" void kernel_launch(void* const* d_in, const int* in_sizes, int n_in,
                              void* d_out, int out_size, void* d_ws, size_t ws_size,
                              hipStream_t stream) {
    const float* x    = (const float*)d_in[0];
    const float* ea   = (const float*)d_in[1];
    const float* W1   = (const float*)d_in[2];
    const float* b1   = (const float*)d_in[3];
    const float* W2   = (const float*)d_in[4];
    const float* b2   = (const float*)d_in[5];
    const float* Wm1  = (const float*)d_in[6];
    const float* bm1  = (const float*)d_in[7];
    const float* Wm2  = (const float*)d_in[8];
    const float* bm2  = (const float*)d_in[9];
    const int*   ei   = (const int*)d_in[10];

    const int N = in_sizes[0] / 5;
    const int E = in_sizes[1] / 4;
    const int* src = ei;
    const int* dst = ei + E;
    float* out = (float*)d_out;

    char* ws = (char*)d_ws;
    size_t off = 0;
    auto alloc = [&](size_t bytes) -> void* {
        void* p = ws + off;
        off = (off + bytes + 255) & ~(size_t)255;
        return p;
    };
    int*   cnt    = (int*)alloc((size_t)N * 4);
    int*   rowptr = (int*)alloc((size_t)(N + 1) * 4);
    int*   cursor = (int*)alloc((size_t)N * 4);
    int*   bsum   = (int*)alloc(256 * 4);
    float* dis    = (float*)alloc((size_t)N * 4);
    int4*  csr    = (int4*)alloc((size_t)(E + 8) * 16);
    int*   csrc   = (int*)alloc((size_t)(E + 8) * 4);
    uint*  R1     = (uint*)alloc((size_t)N * 128 * 4);  // full HsHd [N][256] bf16
    uint*  hbuf   = (uint*)alloc((size_t)N * 64 * 4);   // bf16 h1 -> h
    uint*  fW2    = (uint*)alloc(8192 * 4);
    uint*  fWm1   = (uint*)alloc(16384 * 4);
    (void)ws_size; (void)n_in; (void)out_size;

    uint* xws  = R1;        // [N][64] uint (bf16 x 128)
    uint* HsHd = R1;        // [N][128] uint (bf16 x 256)

    const int NB = (N + 255) / 256;
    const int EB = (E + 255) / 256;

    // setup
    zero_prep<<<NB, 256, 0, stream>>>(cnt, N, W2, Wm1, fW2, fWm1);
    hist_kernel<<<EB, 256, 0, stream>>>(dst, cnt, E);
    scan1<<<NB, 256, 0, stream>>>(cnt, rowptr, bsum, N);
    scan3x<<<NB, 256, 0, stream>>>(cnt, rowptr, bsum, cursor, dis, N, E, NB);
    scatter_xw1<<<EB, 256, 0, stream>>>(src, dst, cursor, csr, csrc, E, x, W1, dis, xws, N);

    // GCN layer 1: h1 = relu(b1 + dis*agg(xws1))
    aggregate_kernel<<<(N + 3) / 4, 256, 0, stream>>>((const uint4*)xws, csrc, rowptr, dis,
                                                      b1, (uint4*)hbuf, N, 1);
    // GCN layer 2: xws2 = dis*(h1@W2) [MFMA]; h = b2 + dis*agg(xws2)
    mfma_gemm<<<(N + 63) / 64, 256, 0, stream>>>((const uint4*)hbuf, (const uint4*)fW2,
                                                 b1 /*unused*/, dis,
                                                 (unsigned short*)xws, N, 8, 0);
    aggregate_kernel<<<(N + 3) / 4, 256, 0, stream>>>((const uint4*)xws, csrc, rowptr, dis,
                                                      b2, (uint4*)hbuf, N, 0);
    // edge MLP head: HsHd = h @ [Wm1_top | Wm1_mid] (+bm1 on first 128 cols) [MFMA]
    mfma_gemm<<<(N + 63) / 64, 256, 0, stream>>>((const uint4*)hbuf, (const uint4*)fWm1,
                                                 bm1, nullptr,
                                                 (unsigned short*)HsHd, N, 16, 8);
    // per-edge MLP + sigmoid, edge-parallel over dst-sorted csr
    edge_mlp_kernel<<<2048, 256, 0, stream>>>((const uint4*)HsHd, (const float4*)ea, csr,
                                              Wm1 + 256 * HID, Wm2, bm2, out, E);
}

// Round 7
// 317.044 us; speedup vs baseline: 1.8855x; 1.0255x over previous
//
#include <hip/hip_runtime.h>
#include <math.h>

#define HID 128
typedef unsigned int uint;
typedef __attribute__((ext_vector_type(8))) __bf16 bf16x8;
typedef __attribute__((ext_vector_type(4))) float f32x4;
typedef __attribute__((ext_vector_type(2))) float f32x2;

// ---------------- bf16 helpers (RNE) ----------------

__device__ __forceinline__ uint pack_bf2(float x, float y) {
    union { float f; uint u; } a, b;
    a.f = x; b.f = y;
    uint lo = (a.u + 0x7fffu + ((a.u >> 16) & 1u)) >> 16;
    uint hi = (b.u + 0x7fffu + ((b.u >> 16) & 1u)) & 0xffff0000u;
    return lo | hi;
}

__device__ __forceinline__ unsigned short bf16r(float x) {
    union { float f; uint u; } a; a.f = x;
    return (unsigned short)((a.u + 0x7fffu + ((a.u >> 16) & 1u)) >> 16);
}

__device__ __forceinline__ f32x2 bf2f(uint v) {
    union { uint u[2]; f32x2 f; } r;
    r.u[0] = v << 16;
    r.u[1] = v & 0xffff0000u;
    return r.f;
}

__device__ __forceinline__ f32x2 mk2(float s) { f32x2 r; r.x = s; r.y = s; return r; }
__device__ __forceinline__ f32x2 max2z(f32x2 a) {
    f32x2 r; r.x = fmaxf(a.x, 0.f); r.y = fmaxf(a.y, 0.f); return r;
}
__device__ __forceinline__ f32x2 shfl_xor2(f32x2 v, int m) {
    f32x2 r; r.x = __shfl_xor(v.x, m, 64); r.y = __shfl_xor(v.y, m, 64); return r;
}

// ---------------- setup kernels ----------------

// zero cnt + pad x into xp[N][8] + zero zbias + compute composite weights:
//   Wc = W2 @ [Wm1_top | Wm1_mid]  (128 x 256), stored bf16 in MFMA frag order
//   brow = b2 @ [Wm1_top | Wm1_mid] + [bm1 | 0]  (256)
// frag element (ct,kk,lane,p): Wc[k = kk*32+(lane>>4)*8+2p (+1)][n2 = ct*16+(lane&15)]
__global__ void zero_prep(int* __restrict__ cnt, int N,
                          const float* __restrict__ x, float* __restrict__ xp,
                          const float* __restrict__ W2, const float* __restrict__ Wm1,
                          const float* __restrict__ b2, const float* __restrict__ bm1,
                          uint* __restrict__ fWc, float* __restrict__ brow,
                          float* __restrict__ zbias) {
    int stride = gridDim.x * blockDim.x;
    int t0 = blockIdx.x * blockDim.x + threadIdx.x;
    for (int i = t0; i < N; i += stride) {
        cnt[i] = 0;
        const float* xr = x + (size_t)i * 5;
        float* xo = xp + (size_t)i * 8;
        *(float4*)xo = make_float4(xr[0], xr[1], xr[2], xr[3]);
        xo[4] = xr[4];
    }
    if (t0 < 128) zbias[t0] = 0.f;
    for (int i = t0; i < 16384; i += stride) {      // 16 ct * 4 kk * 64 lanes * 4 pairs
        int p = i & 3, lane = (i >> 2) & 63, kk = (i >> 8) & 3, ct = i >> 10;
        int k = kk * 32 + (lane >> 4) * 8 + p * 2;
        int n2 = ct * 16 + (lane & 15);
        const float* wmc = (n2 < 128) ? (Wm1 + n2) : (Wm1 + 128 * HID + (n2 - 128));
        const float* w2r0 = W2 + (size_t)k * HID;
        const float* w2r1 = w2r0 + HID;
        float d0 = 0.f, d1 = 0.f;
        for (int j = 0; j < HID; ++j) {
            float wm = wmc[(size_t)j * HID];
            d0 += w2r0[j] * wm;
            d1 += w2r1[j] * wm;
        }
        fWc[i] = pack_bf2(d0, d1);
    }
    for (int i = t0; i < 256; i += stride) {
        const float* wmc = (i < 128) ? (Wm1 + i) : (Wm1 + 128 * HID + (i - 128));
        float d = 0.f;
        for (int j = 0; j < HID; ++j) d += b2[j] * wmc[(size_t)j * HID];
        brow[i] = d + ((i < 128) ? bm1[i] : 0.f);
    }
}

__global__ void hist_kernel(const int* __restrict__ dst, int* __restrict__ cnt, int E) {
    int e = blockIdx.x * blockDim.x + threadIdx.x;
    if (e < E) atomicAdd(&cnt[dst[e]], 1);
}

__global__ void scan1(const int* __restrict__ cnt, int* __restrict__ excl,
                      int* __restrict__ bsum, int N) {
    __shared__ int sh[256];
    int tid = threadIdx.x;
    int gid = blockIdx.x * 256 + tid;
    int v = (gid < N) ? cnt[gid] : 0;
    sh[tid] = v;
    __syncthreads();
    for (int o = 1; o < 256; o <<= 1) {
        int t = (tid >= o) ? sh[tid - o] : 0;
        __syncthreads();
        sh[tid] += t;
        __syncthreads();
    }
    if (gid < N) excl[gid] = sh[tid] - v;
    if (tid == 255) bsum[blockIdx.x] = sh[255];
}

// every block redundantly scans bsum (<=256 entries) in LDS, then finalizes its chunk
__global__ void scan3x(const int* __restrict__ cnt, int* __restrict__ rowptr,
                       const int* __restrict__ bsum, int* __restrict__ cursor,
                       float* __restrict__ dis, int N, int E, int NB) {
    __shared__ int sh[256];
    __shared__ int ex[256];
    int tid = threadIdx.x;
    int v = (tid < NB) ? bsum[tid] : 0;
    sh[tid] = v;
    __syncthreads();
    for (int o = 1; o < 256; o <<= 1) {
        int t = (tid >= o) ? sh[tid - o] : 0;
        __syncthreads();
        sh[tid] += t;
        __syncthreads();
    }
    ex[tid] = sh[tid] - v;
    __syncthreads();
    int gid = blockIdx.x * 256 + tid;
    if (gid < N) {
        int r = rowptr[gid] + ex[blockIdx.x];
        rowptr[gid] = r;
        cursor[gid] = r;
        dis[gid] = rsqrtf((float)cnt[gid] + 1.0f);   // deg incl. self-loop
    }
    if (gid == N) rowptr[N] = E;
}

// scatter: csr2 (src|dst<<16, eid), csrc (src), eac (ea in csr order)
__global__ void scatter_kernel(const int* __restrict__ src, const int* __restrict__ dst,
                               int* __restrict__ cursor, uint2* __restrict__ csr2,
                               int* __restrict__ csrc, float4* __restrict__ eac,
                               const float4* __restrict__ ea, int E) {
    int e = blockIdx.x * blockDim.x + threadIdx.x;
    if (e < E) {
        int d = dst[e];
        int s = src[e];
        float4 eav = ea[e];
        int pos = atomicAdd(&cursor[d], 1);
        csr2[pos] = make_uint2((uint)s | ((uint)d << 16), (uint)e);
        csrc[pos] = s;
        eac[pos] = eav;
    }
}

// ---------------- feature kernels ----------------

// sx[n] = dis[n] * ( sum_{in(n)} dis[s]*x[s] + dis[n]*x[n] )   (5 dims, fp32)
// one thread per node; 64 independent chains per wave give natural MLP
__global__ void aggx_kernel(const float* __restrict__ xp, const int* __restrict__ csrc,
                            const int* __restrict__ rowptr, const float* __restrict__ dis,
                            float* __restrict__ sx, int N) {
    int n = blockIdx.x * blockDim.x + threadIdx.x;
    if (n >= N) return;
    int beg = rowptr[n], end = rowptr[n + 1];
    float a0 = 0.f, a1 = 0.f, a2 = 0.f, a3 = 0.f, a4 = 0.f;
    for (int i = beg; i < end; ++i) {
        int s = csrc[i];
        float w = dis[s];
        float4 v = *(const float4*)(xp + (size_t)s * 8);
        float v4 = xp[(size_t)s * 8 + 4];
        a0 += w * v.x; a1 += w * v.y; a2 += w * v.z; a3 += w * v.w; a4 += w * v4;
    }
    float dn = dis[n];
    float4 v = *(const float4*)(xp + (size_t)n * 8);
    float v4 = xp[(size_t)n * 8 + 4];
    a0 += dn * v.x; a1 += dn * v.y; a2 += dn * v.z; a3 += dn * v.w; a4 += dn * v4;
    float* o = sx + (size_t)n * 8;
    *(float4*)o = make_float4(dn * a0, dn * a1, dn * a2, dn * a3);
    o[4] = dn * a4;
}

// hs1 = dis * relu(sx @ W1 + b1), bf16-packed.  sx row is wave-uniform (scalar loads).
__global__ void hs1_kernel(const float* __restrict__ sx, const float* __restrict__ W1,
                           const float* __restrict__ b1, const float* __restrict__ dis,
                           uint* __restrict__ hs1, int N) {
    int idx = blockIdx.x * blockDim.x + threadIdx.x;
    if (idx >= N * 64) return;
    int n = idx >> 6, p = idx & 63;
    int j = p * 2;
    const float* sr = sx + (size_t)n * 8;
    float a0 = b1[j], a1 = b1[j + 1];
    #pragma unroll
    for (int k = 0; k < 5; ++k) {
        float s = sr[k];
        a0 += s * W1[k * HID + j];
        a1 += s * W1[k * HID + j + 1];
    }
    float dn = dis[n];
    a0 = fmaxf(a0, 0.f) * dn;
    a1 = fmaxf(a1, 0.f) * dn;
    hs1[idx] = pack_bf2(a0, a1);
}

// ---------------- hot kernels ----------------

// 128-dim aggregation: out[n] = bias + dis[n]*( sum_{in(n)} v[s] + v[n] ), bf16 out.
// wave per node; 16-lane group per edge; 4-deep unroll => 16 edges in flight per wave.
__global__ void aggregate_kernel(const uint4* __restrict__ xws, const int* __restrict__ csrc,
                                 const int* __restrict__ rowptr, const float* __restrict__ dis,
                                 const float* __restrict__ bias, uint4* __restrict__ out,
                                 int N, int do_relu) {
    int wave = threadIdx.x >> 6;
    int lane = threadIdx.x & 63;
    int n = blockIdx.x * (blockDim.x >> 6) + wave;
    if (n >= N) return;
    int gl = lane & 15, grp = lane >> 4;
    int beg = rowptr[n], end = rowptr[n + 1];

    f32x2 acc[4];
    #pragma unroll
    for (int p = 0; p < 4; ++p) acc[p] = mk2(0.f);

    for (int base = beg + grp; base < end; base += 16) {
        int i1 = base + 4, i2 = base + 8, i3 = base + 12;
        int s0 = csrc[base];
        int s1 = csrc[(i1 < end) ? i1 : beg];
        int s2 = csrc[(i2 < end) ? i2 : beg];
        int s3 = csrc[(i3 < end) ? i3 : beg];
        uint4 v0 = xws[(size_t)s0 * 16 + gl];
        uint4 v1 = xws[(size_t)s1 * 16 + gl];
        uint4 v2 = xws[(size_t)s2 * 16 + gl];
        uint4 v3 = xws[(size_t)s3 * 16 + gl];
        f32x2 w1 = mk2((i1 < end) ? 1.f : 0.f);
        f32x2 w2 = mk2((i2 < end) ? 1.f : 0.f);
        f32x2 w3 = mk2((i3 < end) ? 1.f : 0.f);
        acc[0] += bf2f(v0.x);  acc[1] += bf2f(v0.y);
        acc[2] += bf2f(v0.z);  acc[3] += bf2f(v0.w);
        acc[0] += bf2f(v1.x) * w1;  acc[1] += bf2f(v1.y) * w1;
        acc[2] += bf2f(v1.z) * w1;  acc[3] += bf2f(v1.w) * w1;
        acc[0] += bf2f(v2.x) * w2;  acc[1] += bf2f(v2.y) * w2;
        acc[2] += bf2f(v2.z) * w2;  acc[3] += bf2f(v2.w) * w2;
        acc[0] += bf2f(v3.x) * w3;  acc[1] += bf2f(v3.y) * w3;
        acc[2] += bf2f(v3.z) * w3;  acc[3] += bf2f(v3.w) * w3;
    }
    #pragma unroll
    for (int p = 0; p < 4; ++p) {
        acc[p] += shfl_xor2(acc[p], 16);
        acc[p] += shfl_xor2(acc[p], 32);
    }

    if (grp == 0) {
        uint4 sv = xws[(size_t)n * 16 + gl];
        f32x2 dn = mk2(dis[n]);
        const float* bp = bias + gl * 8;
        f32x2 o[4];
        o[0] = (acc[0] + bf2f(sv.x)) * dn + *(const f32x2*)(bp);
        o[1] = (acc[1] + bf2f(sv.y)) * dn + *(const f32x2*)(bp + 2);
        o[2] = (acc[2] + bf2f(sv.z)) * dn + *(const f32x2*)(bp + 4);
        o[3] = (acc[3] + bf2f(sv.w)) * dn + *(const f32x2*)(bp + 6);
        if (do_relu) {
            #pragma unroll
            for (int p = 0; p < 4; ++p) o[p] = max2z(o[p]);
        }
        uint4 pk;
        pk.x = pack_bf2(o[0].x, o[0].y);
        pk.y = pack_bf2(o[1].x, o[1].y);
        pk.z = pack_bf2(o[2].x, o[2].y);
        pk.w = pack_bf2(o[3].x, o[3].y);
        out[(size_t)n * 16 + gl] = pk;
    }
}

// MFMA GEMM: out[N][CT*16] (bf16) = A[N][128]_bf16 @ Bf (+bias for ct<bias_ct)
__launch_bounds__(256)
__global__ void mfma_gemm(const uint4* __restrict__ A, const uint4* __restrict__ Bf,
                          const float* __restrict__ bias, const float* __restrict__ rowscale,
                          unsigned short* __restrict__ out, int N, int CT, int bias_ct) {
    int wave = threadIdx.x >> 6, lane = threadIdx.x & 63;
    int rbase = (blockIdx.x * 4 + wave) * 16;
    if (rbase >= N) return;
    int quad = lane >> 4, gl = lane & 15;
    int r = rbase + gl;
    if (r >= N) r = N - 1;

    bf16x8 afr[4];
    #pragma unroll
    for (int kk = 0; kk < 4; ++kk)
        afr[kk] = *(const bf16x8*)&A[(size_t)r * 16 + kk * 4 + quad];

    float rs[4];
    #pragma unroll
    for (int reg = 0; reg < 4; ++reg) {
        int row = rbase + quad * 4 + reg;
        rs[reg] = (rowscale && row < N) ? rowscale[row] : 1.f;
    }

    int ncols = CT * 16;
    for (int c = 0; c < CT; ++c) {
        f32x4 acc = {0.f, 0.f, 0.f, 0.f};
        #pragma unroll
        for (int kk = 0; kk < 4; ++kk) {
            bf16x8 bfr = *(const bf16x8*)&Bf[(size_t)(c * 4 + kk) * 64 + lane];
            acc = __builtin_amdgcn_mfma_f32_16x16x32_bf16(afr[kk], bfr, acc, 0, 0, 0);
        }
        float bv = (c < bias_ct) ? bias[c * 16 + gl] : 0.f;
        #pragma unroll
        for (int reg = 0; reg < 4; ++reg) {
            int row = rbase + quad * 4 + reg;
            if (row < N)
                out[(size_t)row * ncols + c * 16 + gl] = bf16r((acc[reg] + bv) * rs[reg]);
        }
    }
}

// edge-parallel edge MLP, 2-deep; csr2 8 B/edge; eac sequential.
__launch_bounds__(256)
__global__ void edge_mlp_kernel(const uint4* __restrict__ HsHd, const float4* __restrict__ eac,
                                const uint2* __restrict__ csr2,
                                const float* __restrict__ Wb, const float* __restrict__ Wm2,
                                const float* __restrict__ bm2,
                                float* __restrict__ out, int E) {
    int lane = threadIdx.x & 63;
    int gl = lane & 15, grp = lane >> 4;

    f32x2 wb[4][4], w2[4];
    #pragma unroll
    for (int k = 0; k < 4; ++k) {
        const f32x2* wp = (const f32x2*)(Wb + k * HID + gl * 8);
        #pragma unroll
        for (int p = 0; p < 4; ++p) wb[k][p] = wp[p];
    }
    {
        const f32x2* wp = (const f32x2*)(Wm2 + gl * 8);
        #pragma unroll
        for (int p = 0; p < 4; ++p) w2[p] = wp[p];
    }
    float b2v = bm2[0];

    int gwave = (blockIdx.x * blockDim.x + threadIdx.x) >> 6;
    int nw = (gridDim.x * blockDim.x) >> 6;
    for (int base = gwave * 8; base < E; base += nw * 8) {
        int i0 = base + grp;
        int i1 = i0 + 4;
        int j0 = (i0 < E) ? i0 : (E - 1);
        int j1 = (i1 < E) ? i1 : (E - 1);
        uint2 ce0 = csr2[j0];
        uint2 ce1 = csr2[j1];
        int s0i = ce0.x & 0xffff, d0i = ce0.x >> 16;
        int s1i = ce1.x & 0xffff, d1i = ce1.x >> 16;
        uint4 hv0 = HsHd[(size_t)s0i * 32 + gl];
        uint4 dv0 = HsHd[(size_t)d0i * 32 + 16 + gl];
        uint4 hv1 = HsHd[(size_t)s1i * 32 + gl];
        uint4 dv1 = HsHd[(size_t)d1i * 32 + 16 + gl];
        float4 ea0 = eac[j0];
        float4 ea1 = eac[j1];

        uint hu0[4] = {hv0.x, hv0.y, hv0.z, hv0.w};
        uint du0[4] = {dv0.x, dv0.y, dv0.z, dv0.w};
        uint hu1[4] = {hv1.x, hv1.y, hv1.z, hv1.w};
        uint du1[4] = {dv1.x, dv1.y, dv1.z, dv1.w};

        f32x2 p20 = mk2(0.f), p21 = mk2(0.f);
        f32x2 a0 = mk2(ea0.x), b0 = mk2(ea0.y), c0 = mk2(ea0.z), d0 = mk2(ea0.w);
        f32x2 a1 = mk2(ea1.x), b1 = mk2(ea1.y), c1 = mk2(ea1.z), d1 = mk2(ea1.w);
        #pragma unroll
        for (int p = 0; p < 4; ++p) {
            f32x2 t0 = bf2f(hu0[p]) + bf2f(du0[p]);
            t0 += a0 * wb[0][p];
            t0 += b0 * wb[1][p];
            t0 += c0 * wb[2][p];
            t0 += d0 * wb[3][p];
            t0 = max2z(t0);
            p20 += t0 * w2[p];
            f32x2 t1 = bf2f(hu1[p]) + bf2f(du1[p]);
            t1 += a1 * wb[0][p];
            t1 += b1 * wb[1][p];
            t1 += c1 * wb[2][p];
            t1 += d1 * wb[3][p];
            t1 = max2z(t1);
            p21 += t1 * w2[p];
        }
        float p0 = p20.x + p20.y;
        float p1 = p21.x + p21.y;
        p0 += __shfl_xor(p0, 1, 64);   p1 += __shfl_xor(p1, 1, 64);
        p0 += __shfl_xor(p0, 2, 64);   p1 += __shfl_xor(p1, 2, 64);
        p0 += __shfl_xor(p0, 4, 64);   p1 += __shfl_xor(p1, 4, 64);
        p0 += __shfl_xor(p0, 8, 64);   p1 += __shfl_xor(p1, 8, 64);
        if (gl == 0 && i0 < E) out[ce0.y] = 1.f / (1.f + expf(-(p0 + b2v)));
        if (gl == 0 && i1 < E) out[ce1.y] = 1.f / (1.f + expf(-(p1 + b2v)));
    }
}

// ---------------- launch ----------------

extern "C" void kernel_launch(void* const* d_in, const int* in_sizes, int n_in,
                              void* d_out, int out_size, void* d_ws, size_t ws_size,
                              hipStream_t stream) {
    const float* x    = (const float*)d_in[0];
    const float* ea   = (const float*)d_in[1];
    const float* W1   = (const float*)d_in[2];
    const float* b1   = (const float*)d_in[3];
    const float* W2   = (const float*)d_in[4];
    const float* b2   = (const float*)d_in[5];
    const float* Wm1  = (const float*)d_in[6];
    const float* bm1  = (const float*)d_in[7];
    const float* Wm2  = (const float*)d_in[8];
    const float* bm2  = (const float*)d_in[9];
    const int*   ei   = (const int*)d_in[10];

    const int N = in_sizes[0] / 5;
    const int E = in_sizes[1] / 4;
    const int* src = ei;
    const int* dst = ei + E;
    float* out = (float*)d_out;

    char* ws = (char*)d_ws;
    size_t off = 0;
    auto alloc = [&](size_t bytes) -> void* {
        void* p = ws + off;
        off = (off + bytes + 255) & ~(size_t)255;
        return p;
    };
    int*    cnt    = (int*)alloc((size_t)N * 4);
    int*    rowptr = (int*)alloc((size_t)(N + 1) * 4);
    int*    cursor = (int*)alloc((size_t)N * 4);
    int*    bsum   = (int*)alloc(256 * 4);
    float*  dis    = (float*)alloc((size_t)N * 4);
    uint2*  csr2   = (uint2*)alloc((size_t)(E + 8) * 8);
    int*    csrc   = (int*)alloc((size_t)(E + 8) * 4);
    float4* eac    = (float4*)alloc((size_t)(E + 8) * 16);
    float*  xp     = (float*)alloc((size_t)N * 8 * 4);
    float*  sx     = (float*)alloc((size_t)N * 8 * 4);
    uint*   R      = (uint*)alloc((size_t)N * 128 * 4);  // hs1 [N][64] then HsHd [N][128]
    uint*   g      = (uint*)alloc((size_t)N * 64 * 4);   // S·h1, bf16
    uint*   fWc    = (uint*)alloc(16384 * 4);
    float*  brow   = (float*)alloc(256 * 4);
    float*  zbias  = (float*)alloc(128 * 4);
    (void)ws_size; (void)n_in; (void)out_size;

    uint* hs1  = R;   // [N][64] uint (bf16 x 128) = dis * relu(sx@W1 + b1)
    uint* HsHd = R;   // [N][128] uint (bf16 x 256), overwrites hs1 (dead by then)

    const int NB = (N + 255) / 256;
    const int EB = (E + 255) / 256;

    // setup
    zero_prep<<<NB, 256, 0, stream>>>(cnt, N, x, xp, W2, Wm1, b2, bm1, fWc, brow, zbias);
    hist_kernel<<<EB, 256, 0, stream>>>(dst, cnt, E);
    scan1<<<NB, 256, 0, stream>>>(cnt, rowptr, bsum, N);
    scan3x<<<NB, 256, 0, stream>>>(cnt, rowptr, bsum, cursor, dis, N, E, NB);
    scatter_kernel<<<EB, 256, 0, stream>>>(src, dst, cursor, csr2, csrc, eac,
                                           (const float4*)ea, E);

    // layer 1 via commuted aggregation: sx = S·x (5-dim), hs1 = dis*relu(sx@W1+b1)
    aggx_kernel<<<NB, 256, 0, stream>>>(xp, csrc, rowptr, dis, sx, N);
    hs1_kernel<<<(N * 64 + 255) / 256, 256, 0, stream>>>(sx, W1, b1, dis, hs1, N);

    // g = S·h1  (the single 128-dim aggregate)
    aggregate_kernel<<<(N + 3) / 4, 256, 0, stream>>>((const uint4*)hs1, csrc, rowptr, dis,
                                                      zbias, (uint4*)g, N, 0);

    // HsHd = g @ Wc + brow   (fused W2 and Wm1 head GEMMs)
    mfma_gemm<<<(N + 63) / 64, 256, 0, stream>>>((const uint4*)g, (const uint4*)fWc,
                                                 brow, nullptr,
                                                 (unsigned short*)HsHd, N, 16, 16);

    // per-edge MLP + sigmoid
    edge_mlp_kernel<<<2048, 256, 0, stream>>>((const uint4*)HsHd, (const float4*)eac, csr2,
                                              Wm1 + 256 * HID, Wm2, bm2, out, E);
}